// Round 4
// baseline (435.568 us; speedup 1.0000x reference)
//
#include <hip/hip_runtime.h>
#include <hip/hip_bf16.h>

// ---------------------------------------------------------------------------
// MultiHeadAttention_21887153340754
// N=4096, IN=1000(pad 1024), H1=2048, H2=1024, EMB=512, HEADS=8, depth=64, OUT=1000
//
// Attention is LINEAR in scores (no softmax):
//   att_h = (q̂_h @ M_h / 8) / den,  M_h = k̂_h^T @ v_h (64x64),
//   den[n,h] = (q̂_h[n]·ksum_h)/8 + 1e-8
// and the output projection distributes over heads:
//   out = Σ_h (q̂_h/8/den) @ (M_h @ Wo_h) + b  =  q̃ @ MW + b
// => attention + out-proj = two tiny kernels + one [4096,512]@[512,1000] GEMM.
//
// Round 4: (1) drop forced lgkmcnt(0) in gemm_p8 (compiler emits counted
// waits; ks0 reads issued first), (2) XCD-bijective grid swizzle (T1),
// (3) fuse attention into out-proj via q-prescale + MW precompute.
// ---------------------------------------------------------------------------

typedef __attribute__((ext_vector_type(4))) float f32x4;
typedef __attribute__((ext_vector_type(8))) short bf16x8;

// ---- workspace layout (bytes) ---------------------------------------------
static constexpr size_t OFF_XB   = 0;                      // bf16 [4096][1024]
static constexpr size_t OFF_WT1  = OFF_XB   + 8388608;     // bf16 [6144][1024]
static constexpr size_t OFF_WT2  = OFF_WT1  + 12582912;    // bf16 [3][1024][2048]
static constexpr size_t OFF_WT3  = OFF_WT2  + 12582912;    // bf16 [3][512][1024]
static constexpr size_t OFF_MWT  = OFF_WT3  + 3145728;     // bf16 [1024][512]  (MW^T)
static constexpr size_t OFF_B1C  = OFF_MWT  + 1048576;     // f32  [6144]
static constexpr size_t OFF_H1   = OFF_B1C  + 24576;       // bf16 [4096][6144]
static constexpr size_t OFF_H2   = OFF_H1   + 50331648;    // bf16 [4096][3072]
static constexpr size_t OFF_QKV  = OFF_H2   + 25165824;    // bf16 [4096][1536]
static constexpr size_t OFF_MP   = OFF_QKV  + 12582912;    // f32  [32][8][4160]
static constexpr size_t OFF_MF   = OFF_MP   + 4259840;     // f32  [8][4160]
static constexpr size_t OFF_QT   = OFF_MF   + 133120;      // bf16 [4096][512]  (q̃)

__device__ __forceinline__ void gload16(const __hip_bfloat16* g, __hip_bfloat16* l) {
  __builtin_amdgcn_global_load_lds(
      (const __attribute__((address_space(1))) void*)g,
      (__attribute__((address_space(3))) void*)l, 16, 0, 0);
}

// XCD-bijective chunk swizzle (m204): contiguous grid chunks per XCD
__device__ __forceinline__ int xcd_swz(int orig, int nwg) {
  const int qq = nwg >> 3, rr = nwg & 7;
  const int xcd = orig & 7, off = orig >> 3;
  return (xcd < rr) ? (xcd * (qq + 1) + off)
                    : (rr * (qq + 1) + (xcd - rr) * qq + off);
}

// ---- batch fp32 [4096][1000] -> bf16 [4096][1024] (zero pad) --------------
__global__ void conv_pad_batch(const float* __restrict__ in, __hip_bfloat16* __restrict__ out) {
  int idx = blockIdx.x * 256 + threadIdx.x;
  int r = idx >> 10, c = idx & 1023;
  float v = (c < 1000) ? in[(size_t)r * 1000 + c] : 0.f;
  out[idx] = __float2bfloat16(v);
}

__global__ void concat3(const float* __restrict__ a, const float* __restrict__ b,
                        const float* __restrict__ c, float* __restrict__ out) {
  int i = blockIdx.x * 256 + threadIdx.x;
  if (i < 6144) {
    const float* src = (i < 2048) ? a : ((i < 4096) ? b : c);
    out[i] = src[i & 2047];
  }
}

// ---- W [K][N] fp32 -> Wt [Npad][Kpad] bf16, batched over z ----------------
__global__ void transpose_conv3(const float* __restrict__ s0, const float* __restrict__ s1,
                                const float* __restrict__ s2, __hip_bfloat16* __restrict__ outb,
                                size_t ostride, int K, int N, int Kpad) {
  const float* in = (blockIdx.z == 0) ? s0 : ((blockIdx.z == 1) ? s1 : s2);
  __hip_bfloat16* out = outb + (size_t)blockIdx.z * ostride;
  __shared__ float tile[32][33];
  int kb = blockIdx.x * 32, nb = blockIdx.y * 32;
  int tx = threadIdx.x, ty = threadIdx.y;            // block (32,8)
  for (int i = ty; i < 32; i += 8) {
    int k = kb + i, n = nb + tx;
    tile[i][tx] = (k < K && n < N) ? in[(size_t)k * N + n] : 0.f;
  }
  __syncthreads();
  for (int i = ty; i < 32; i += 8) {
    int n = nb + i, kp = kb + tx;
    out[(size_t)n * Kpad + kp] = __float2bfloat16(tile[tx][i]);
  }
}

// ---------------------------------------------------------------------------
// gemm_p8: 256x256 tile, BK=64, 8 waves, 8-phase schedule, counted vmcnt.
// (See round-3 ledger comments; this round: no forced lgkmcnt(0) — ks0 reads
// issued first so the compiler's counted lgkm waits overlap ks1 returns.)
// ---------------------------------------------------------------------------
__global__ __launch_bounds__(512, 2) void gemm_p8(
    const __hip_bfloat16* __restrict__ A, int lda, size_t Az,
    const __hip_bfloat16* __restrict__ B, int ldb, size_t Bz,
    const float* __restrict__ bias0, const float* __restrict__ bias1,
    const float* __restrict__ bias2,
    __hip_bfloat16* __restrict__ Cout, int ldc, size_t Cz,
    int NT, int relu) {
  __shared__ __hip_bfloat16 sm[2][4][8192];          // [buf][A0,A1,B0,B1][128*64]
  const int t = threadIdx.x;
  const int z = blockIdx.z;
  const int gx = gridDim.x;
  const int id2 = xcd_swz(blockIdx.y * gx + blockIdx.x, gx * gridDim.y);
  const int m0 = (id2 / gx) * 256, n0 = (id2 % gx) * 256;
  A += (size_t)z * Az;
  B += (size_t)z * Bz;
  const float* bias = (z == 0) ? bias0 : ((z == 1) ? bias1 : bias2);

  const int w = t >> 6, l = t & 63;
  const int wm = w >> 2, wn = w & 3;
  const int fr = l & 15, fq = l >> 4;

  const int row0 = t >> 3, row1 = row0 + 64;
  const int c0 = (t & 7) ^ (row0 & 7);
  const int c1 = (t & 7) ^ (row1 & 7);
  const __hip_bfloat16* gA0a = A + (size_t)(m0 + row0) * lda + c0 * 8;
  const __hip_bfloat16* gA0b = A + (size_t)(m0 + row1) * lda + c1 * 8;
  const __hip_bfloat16* gA1a = gA0a + (size_t)128 * lda;
  const __hip_bfloat16* gA1b = gA0b + (size_t)128 * lda;
  const __hip_bfloat16* gB0a = B + (size_t)(n0 + row0) * ldb + c0 * 8;
  const __hip_bfloat16* gB0b = B + (size_t)(n0 + row1) * ldb + c1 * 8;
  const __hip_bfloat16* gB1a = gB0a + (size_t)128 * ldb;
  const __hip_bfloat16* gB1b = gB0b + (size_t)128 * ldb;

  const int baseA = (wm * 64 + fr) * 128;
  const int baseB = (wn * 32 + fr) * 128;
  const int xb0 = ((fq) ^ (fr & 7)) * 16;
  const int xb1 = ((4 + fq) ^ (fr & 7)) * 16;

  f32x4 acc[8][4] = {};
  bf16x8 af[4][2], bfv[2][2];

#define STG8(NXT, HALF, PA, PB, KT) do {                                       \
    gload16((PA) + (size_t)(KT) * 64, &sm[NXT][HALF][w * 512]);                \
    gload16((PB) + (size_t)(KT) * 64, &sm[NXT][HALF][w * 512 + 4096]);         \
  } while (0)

#define PH8(CUR, MG, NG, RDA, RDB, STG, WAITSTMT) do {                         \
    const char* a_ = (const char*)&sm[CUR][MG][0];                             \
    const char* b_ = (const char*)&sm[CUR][2 + (NG)][0];                       \
    if (RDA) {                                                                 \
      _Pragma("unroll") for (int i = 0; i < 4; ++i)                            \
        af[i][0] = *(const bf16x8*)(a_ + baseA + i * 2048 + xb0);              \
    }                                                                          \
    if (RDB) {                                                                 \
      _Pragma("unroll") for (int j = 0; j < 2; ++j)                            \
        bfv[j][0] = *(const bf16x8*)(b_ + baseB + j * 2048 + xb0);             \
    }                                                                          \
    if (RDA) {                                                                 \
      _Pragma("unroll") for (int i = 0; i < 4; ++i)                            \
        af[i][1] = *(const bf16x8*)(a_ + baseA + i * 2048 + xb1);              \
    }                                                                          \
    if (RDB) {                                                                 \
      _Pragma("unroll") for (int j = 0; j < 2; ++j)                            \
        bfv[j][1] = *(const bf16x8*)(b_ + baseB + j * 2048 + xb1);             \
    }                                                                          \
    STG;                                                                       \
    __builtin_amdgcn_s_barrier();                                              \
    __builtin_amdgcn_sched_barrier(0);                                         \
    __builtin_amdgcn_s_setprio(1);                                             \
    _Pragma("unroll") for (int ks = 0; ks < 2; ++ks)                           \
      _Pragma("unroll") for (int i = 0; i < 4; ++i)                            \
        _Pragma("unroll") for (int j = 0; j < 2; ++j)                          \
          acc[(MG) * 4 + i][(NG) * 2 + j] =                                    \
              __builtin_amdgcn_mfma_f32_16x16x32_bf16(                         \
                  af[i][ks], bfv[j][ks], acc[(MG) * 4 + i][(NG) * 2 + j],      \
                  0, 0, 0);                                                    \
    __builtin_amdgcn_s_setprio(0);                                             \
    WAITSTMT;                                                                  \
    __builtin_amdgcn_s_barrier();                                              \
  } while (0)

  // prologue: stage all 4 halves of tile 0 into buf 0, drain, barrier
  STG8(0, 0, gA0a, gA0b, 0);
  STG8(0, 1, gA1a, gA1b, 0);
  STG8(0, 2, gB0a, gB0b, 0);
  STG8(0, 3, gB1a, gB1b, 0);
  asm volatile("s_waitcnt vmcnt(0)" ::: "memory");
  __builtin_amdgcn_s_barrier();

  for (int T = 0; T < NT - 1; ++T) {
    const int cur = T & 1, nxt = cur ^ 1;
    const int kt = T + 1;
    PH8(cur, 0, 0, 1, 1, STG8(nxt, 0, gA0a, gA0b, kt), (void)0);
    PH8(cur, 1, 0, 1, 0, STG8(nxt, 1, gA1a, gA1b, kt),
        asm volatile("s_waitcnt vmcnt(4)" ::: "memory"));
    PH8(cur, 1, 1, 0, 1, STG8(nxt, 2, gB0a, gB0b, kt), (void)0);
    PH8(cur, 0, 1, 1, 0, STG8(nxt, 3, gB1a, gB1b, kt),
        asm volatile("s_waitcnt vmcnt(2)" ::: "memory"));
  }
  {
    const int cur = (NT - 1) & 1;
    PH8(cur, 0, 0, 1, 1, (void)0, (void)0);
    PH8(cur, 1, 0, 1, 0, (void)0,
        asm volatile("s_waitcnt vmcnt(0)" ::: "memory"));
    PH8(cur, 1, 1, 0, 1, (void)0, (void)0);
    PH8(cur, 0, 1, 1, 0, (void)0, (void)0);
  }
#undef PH8
#undef STG8

  // epilogue: quarter-split mapping
  __hip_bfloat16* C = Cout + (size_t)z * Cz;
  float bv[4];
#pragma unroll
  for (int nj = 0; nj < 4; ++nj) {
    const int col = n0 + (nj >> 1) * 128 + wn * 32 + (nj & 1) * 16 + fr;
    bv[nj] = bias[col];
  }
#pragma unroll
  for (int mi = 0; mi < 8; ++mi) {
    const int rowb = m0 + (mi >> 2) * 128 + wm * 64 + (mi & 3) * 16 + fq * 4;
#pragma unroll
    for (int nj = 0; nj < 4; ++nj) {
      const int col = n0 + (nj >> 1) * 128 + wn * 32 + (nj & 1) * 16 + fr;
#pragma unroll
      for (int rr = 0; rr < 4; ++rr) {
        float v = acc[mi][nj][rr] + bv[nj];
        if (relu) v = fmaxf(v, 0.f);
        C[(size_t)(rowb + rr) * ldc + col] = __float2bfloat16(v);
      }
    }
  }
}

// ---- generalized 128^2 m97-style GEMM (small shapes: G3, out-proj) --------
// epi: 0 = bf16, 1 = bf16+relu, 2 = f32 store guarded col<nlimit,
//      3 = bf16 + relu iff z<2
__global__ __launch_bounds__(256) void gemm_bt(
    const __hip_bfloat16* __restrict__ A, int lda, size_t Az,
    const __hip_bfloat16* __restrict__ B, int ldb, size_t Bz,
    const float* __restrict__ bias0, const float* __restrict__ bias1,
    const float* __restrict__ bias2,
    void* __restrict__ Cout, int ldc, size_t Cz,
    int nlimit, int K, int epi) {
  __shared__ __hip_bfloat16 As[128 * 32];
  __shared__ __hip_bfloat16 Bs[128 * 32];
  const int t = threadIdx.x;
  const int z = blockIdx.z;
  const int gx = gridDim.x;
  const int id2 = xcd_swz(blockIdx.y * gx + blockIdx.x, gx * gridDim.y);
  const int m0 = (id2 / gx) * 128, n0 = (id2 % gx) * 128;
  A += (size_t)z * Az;
  B += (size_t)z * Bz;
  const float* bias = (z == 0) ? bias0 : ((z == 1) ? bias1 : bias2);
  const int w = t >> 6, l = t & 63;
  const int wm = (w >> 1) * 64, wn = (w & 1) * 64;
  const int fr = l & 15, fq = l >> 4;
  const int sr = t >> 2, sc = (t & 3) * 8;

  f32x4 acc[4][4] = {};

  const __hip_bfloat16* ga = A + (size_t)(m0 + sr) * lda + sc;
  const __hip_bfloat16* gb = B + (size_t)(n0 + sr) * ldb + sc;
  __hip_bfloat16* la = As + w * 512;
  __hip_bfloat16* lb = Bs + w * 512;

  for (int k0 = 0; k0 < K; k0 += 32) {
    gload16(ga, la);
    gload16(ga + (size_t)64 * lda, la + 2048);
    gload16(gb, lb);
    gload16(gb + (size_t)64 * ldb, lb + 2048);
    ga += 32; gb += 32;
    __syncthreads();
    bf16x8 af[4], bfr[4];
#pragma unroll
    for (int i = 0; i < 4; ++i) {
      af[i]  = *reinterpret_cast<const bf16x8*>(&As[(wm + i * 16 + fr) * 32 + fq * 8]);
      bfr[i] = *reinterpret_cast<const bf16x8*>(&Bs[(wn + i * 16 + fr) * 32 + fq * 8]);
    }
#pragma unroll
    for (int i = 0; i < 4; ++i)
#pragma unroll
      for (int j = 0; j < 4; ++j)
        acc[i][j] = __builtin_amdgcn_mfma_f32_16x16x32_bf16(af[i], bfr[j], acc[i][j], 0, 0, 0);
    __syncthreads();
  }

  const bool dorelu = (epi == 1) || (epi == 3 && z < 2);
  float bv[4];
#pragma unroll
  for (int j = 0; j < 4; ++j) {
    int col = n0 + wn + j * 16 + fr;
    bv[j] = (col < nlimit) ? bias[col] : 0.f;
  }
#pragma unroll
  for (int i = 0; i < 4; ++i) {
#pragma unroll
    for (int j = 0; j < 4; ++j) {
      int col = n0 + wn + j * 16 + fr;
#pragma unroll
      for (int r = 0; r < 4; ++r) {
        int row = m0 + wm + i * 16 + fq * 4 + r;
        float v = acc[i][j][r] + bv[j];
        if (dorelu) v = fmaxf(v, 0.f);
        if (epi == 2) {
          if (col < nlimit)
            ((float*)Cout)[(size_t)row * ldc + col] = v;
        } else {
          ((__hip_bfloat16*)Cout + (size_t)z * Cz)[(size_t)row * ldc + col] = __float2bfloat16(v);
        }
      }
    }
  }
}

// ---- per-head partial M = kh^T vh (64x64) and ksum, over 128-row chunks ---
__global__ __launch_bounds__(256) void kv_outer(const __hip_bfloat16* __restrict__ QKV, int ld,
                                                float* __restrict__ part) {
  __shared__ __hip_bfloat16 kt[128][64];
  __shared__ __hip_bfloat16 vt[128][64];
  const int t = threadIdx.x;
  const int n0 = blockIdx.x * 128;
  const int h = blockIdx.y;
#pragma unroll
  for (int it = 0; it < 4; ++it) {
    int r = it * 32 + (t >> 3);
    int c = (t & 7) * 8;
    const __hip_bfloat16* kr = &QKV[(size_t)(n0 + r) * ld + 512 + h * 64 + c];
    const __hip_bfloat16* vr = &QKV[(size_t)(n0 + r) * ld + 1024 + h * 64 + c];
    *reinterpret_cast<bf16x8*>(&kt[r][c]) = *reinterpret_cast<const bf16x8*>(kr);
    *reinterpret_cast<bf16x8*>(&vt[r][c]) = *reinterpret_cast<const bf16x8*>(vr);
  }
  __syncthreads();
  const int i = t >> 2, j0 = (t & 3) << 4;
  float acc[16] = {};
  float ks = 0.f;
  for (int r = 0; r < 128; ++r) {
    float kv = __bfloat162float(kt[r][i]);
    ks += kv;
#pragma unroll
    for (int jj = 0; jj < 16; ++jj)
      acc[jj] += kv * __bfloat162float(vt[r][j0 + jj]);
  }
  float* dst = part + ((size_t)blockIdx.x * 8 + h) * 4160;
#pragma unroll
  for (int jj = 0; jj < 16; ++jj) dst[i * 64 + j0 + jj] = acc[jj];
  if ((t & 3) == 0) dst[4096 + i] = ks;
}

__global__ void reduce_m(const float* __restrict__ part, float* __restrict__ Mfin) {
  int h = blockIdx.x, t = threadIdx.x;
  for (int idx = t; idx < 4160; idx += 256) {
    float s = 0.f;
    for (int c = 0; c < 32; ++c) s += part[((size_t)c * 8 + h) * 4160 + idx];
    Mfin[(size_t)h * 4160 + idx] = s;
  }
}

// ---- MW^T[j][h*64+i] = sum_d M[h][i*64+d] * Wo[h*64+d][j]  (bf16 out) -----
__global__ void mw_kernel(const float* __restrict__ Mfin, const float* __restrict__ wo,
                          __hip_bfloat16* __restrict__ MWT) {
  const int h = blockIdx.y;
  const int j = blockIdx.x * 64 + threadIdx.x;       // grid (16,8), block 64
  const float* M = Mfin + (size_t)h * 4160;
  if (j < 1000) {
    for (int i = 0; i < 64; ++i) {
      float a = 0.f;
      for (int d = 0; d < 64; ++d)
        a += M[i * 64 + d] * wo[(size_t)(h * 64 + d) * 1000 + j];
      MWT[(size_t)j * 512 + h * 64 + i] = __float2bfloat16(a);
    }
  } else {
    for (int i = 0; i < 64; ++i)
      MWT[(size_t)j * 512 + h * 64 + i] = __float2bfloat16(0.f);
  }
}

// ---- q̃[n][h*64+:] = q̂ * 0.125 / den[n,h],  den = (q̂·ksum_h)/8 + 1e-8 ----
__global__ __launch_bounds__(256) void qscale(const __hip_bfloat16* __restrict__ QKV,
                                              const float* __restrict__ Mfin,
                                              __hip_bfloat16* __restrict__ QT) {
  const int t = threadIdx.x;
  const int r = blockIdx.x * 4 + (t >> 6);           // 1024 blocks, 4 rows each
  const int c = (t & 63) * 8;
  const int h = (t & 63) >> 3;
  bf16x8 qv = *reinterpret_cast<const bf16x8*>(&QKV[(size_t)r * 1536 + c]);
  float qf[8];
#pragma unroll
  for (int j = 0; j < 8; ++j)
    qf[j] = __bfloat162float(*(const __hip_bfloat16*)&((const short*)&qv)[j]);
  const float* ks = Mfin + (size_t)h * 4160 + 4096 + (c & 63);
  float s = 0.f;
#pragma unroll
  for (int j = 0; j < 8; ++j) s += qf[j] * ks[j];
  s += __shfl_xor(s, 1, 8);
  s += __shfl_xor(s, 2, 8);
  s += __shfl_xor(s, 4, 8);
  const float inv = 0.125f / (s * 0.125f + 1e-8f);
  bf16x8 o;
#pragma unroll
  for (int j = 0; j < 8; ++j) {
    __hip_bfloat16 b = __float2bfloat16(qf[j] * inv);
    ((short*)&o)[j] = *(const short*)&b;
  }
  *reinterpret_cast<bf16x8*>(&QT[(size_t)r * 512 + c]) = o;
}

// ---------------------------------------------------------------------------
extern "C" void kernel_launch(void* const* d_in, const int* in_sizes, int n_in,
                              void* d_out, int out_size, void* d_ws, size_t ws_size,
                              hipStream_t stream) {
  const float* batch = (const float*)d_in[0];
  const float* w1[3] = {(const float*)d_in[1],  (const float*)d_in[7],  (const float*)d_in[13]};
  const float* b1[3] = {(const float*)d_in[2],  (const float*)d_in[8],  (const float*)d_in[14]};
  const float* w2[3] = {(const float*)d_in[3],  (const float*)d_in[9],  (const float*)d_in[15]};
  const float* b2[3] = {(const float*)d_in[4],  (const float*)d_in[10], (const float*)d_in[16]};
  const float* w3[3] = {(const float*)d_in[5],  (const float*)d_in[11], (const float*)d_in[17]};
  const float* b3[3] = {(const float*)d_in[6],  (const float*)d_in[12], (const float*)d_in[18]};
  const float* wow   = (const float*)d_in[19];
  const float* wob   = (const float*)d_in[20];

  char* ws = (char*)d_ws;
  __hip_bfloat16* XB  = (__hip_bfloat16*)(ws + OFF_XB);
  __hip_bfloat16* WT1 = (__hip_bfloat16*)(ws + OFF_WT1);
  __hip_bfloat16* WT2 = (__hip_bfloat16*)(ws + OFF_WT2);
  __hip_bfloat16* WT3 = (__hip_bfloat16*)(ws + OFF_WT3);
  __hip_bfloat16* MWT = (__hip_bfloat16*)(ws + OFF_MWT);
  float*          B1C = (float*)(ws + OFF_B1C);
  __hip_bfloat16* H1  = (__hip_bfloat16*)(ws + OFF_H1);
  __hip_bfloat16* H2  = (__hip_bfloat16*)(ws + OFF_H2);
  __hip_bfloat16* QKV = (__hip_bfloat16*)(ws + OFF_QKV);
  float*          MP  = (float*)(ws + OFF_MP);
  float*          MF  = (float*)(ws + OFF_MF);
  __hip_bfloat16* QT  = (__hip_bfloat16*)(ws + OFF_QT);
  float*          OUT = (float*)d_out;

  // 1) input conversion / weight transposition (batched over z)
  conv_pad_batch<<<16384, 256, 0, stream>>>(batch, XB);
  concat3<<<24, 256, 0, stream>>>(b1[0], b1[1], b1[2], B1C);
  transpose_conv3<<<dim3(32, 64, 3), dim3(32, 8), 0, stream>>>(
      w1[0], w1[1], w1[2], WT1, (size_t)2048 * 1024, 1000, 2048, 1024);
  transpose_conv3<<<dim3(64, 32, 3), dim3(32, 8), 0, stream>>>(
      w2[0], w2[1], w2[2], WT2, (size_t)1024 * 2048, 2048, 1024, 2048);
  transpose_conv3<<<dim3(32, 16, 3), dim3(32, 8), 0, stream>>>(
      w3[0], w3[1], w3[2], WT3, (size_t)512 * 1024, 1024, 512, 1024);

  // 2) MLPs
  // G1 (merged q|k|v): [4096,1024] @ [1024,6144] -> H1 (relu)  [8-phase 256^2]
  gemm_p8<<<dim3(24, 16, 1), 512, 0, stream>>>(XB, 1024, 0, WT1, 1024, 0,
                                               B1C, B1C, B1C, H1, 6144, 0, 16, 1);
  // G2 z-batched: [4096,2048] @ [2048,1024] -> H2 (relu)       [8-phase 256^2]
  gemm_p8<<<dim3(4, 16, 3), 512, 0, stream>>>(H1, 6144, 2048, WT2, 2048, (size_t)1024 * 2048,
                                              b2[0], b2[1], b2[2], H2, 3072, 1024, 32, 1);
  // G3 z-batched: [4096,1024] @ [1024,512] -> QKV (q,k relu; v plain) [128^2]
  gemm_bt<<<dim3(4, 32, 3), 256, 0, stream>>>(H2, 3072, 1024, WT3, 1024, (size_t)512 * 1024,
                                              b3[0], b3[1], b3[2], QKV, 1536, 512,
                                              512, 1024, 3);

  // 3) attention reductions + fusion into out-proj operands
  kv_outer<<<dim3(32, 8), 256, 0, stream>>>(QKV, 1536, MP);
  reduce_m<<<8, 256, 0, stream>>>(MP, MF);
  mw_kernel<<<dim3(16, 8), 64, 0, stream>>>(MF, wow, MWT);
  qscale<<<1024, 256, 0, stream>>>(QKV, MF, QT);

  // 4) fused attention+output projection: q̃ @ MW^T -> d_out fp32 [128^2]
  gemm_bt<<<dim3(8, 32, 1), 256, 0, stream>>>(QT, 512, 0, MWT, 512, 0,
                                              wob, wob, wob, OUT, 1000, 0,
                                              1000, 512, 2);

  (void)in_sizes; (void)n_in; (void)out_size; (void)ws_size;
}

// Round 5
// 304.692 us; speedup vs baseline: 1.4295x; 1.4295x over previous
//
#include <hip/hip_runtime.h>
#include <hip/hip_bf16.h>

// ---------------------------------------------------------------------------
// MultiHeadAttention_21887153340754
// N=4096, IN=1000(pad 1024), H1=2048, H2=1024, EMB=512, HEADS=8, depth=64, OUT=1000
//
// Attention is LINEAR in scores (no softmax):
//   att_h = (q̂_h @ M_h / 8) / den,  M_h = k̂_h^T @ v_h (64x64),
//   den[n,h] = (q̂_h[n]·ksum_h)/8 + 1e-8
// and the output projection distributes over heads:
//   out = Σ_h (q̂_h/8/den) @ (M_h @ Wo_h) + b  =  q̃ @ MW + b
// => attention + out-proj = two tiny kernels + one [4096,512]@[512,1000] GEMM.
//
// Round 5: fix mw_kernel (was 170 µs at 1% util: strided wo re-reads).
// Now: M_h staged in LDS, wo columns loaded coalesced once into registers,
// 64x64 register FMAs, contiguous vector stores. Everything else unchanged.
// ---------------------------------------------------------------------------

typedef __attribute__((ext_vector_type(4))) float f32x4;
typedef __attribute__((ext_vector_type(8))) short bf16x8;

// ---- workspace layout (bytes) ---------------------------------------------
static constexpr size_t OFF_XB   = 0;                      // bf16 [4096][1024]
static constexpr size_t OFF_WT1  = OFF_XB   + 8388608;     // bf16 [6144][1024]
static constexpr size_t OFF_WT2  = OFF_WT1  + 12582912;    // bf16 [3][1024][2048]
static constexpr size_t OFF_WT3  = OFF_WT2  + 12582912;    // bf16 [3][512][1024]
static constexpr size_t OFF_MWT  = OFF_WT3  + 3145728;     // bf16 [1024][512]  (MW^T)
static constexpr size_t OFF_B1C  = OFF_MWT  + 1048576;     // f32  [6144]
static constexpr size_t OFF_H1   = OFF_B1C  + 24576;       // bf16 [4096][6144]
static constexpr size_t OFF_H2   = OFF_H1   + 50331648;    // bf16 [4096][3072]
static constexpr size_t OFF_QKV  = OFF_H2   + 25165824;    // bf16 [4096][1536]
static constexpr size_t OFF_MP   = OFF_QKV  + 12582912;    // f32  [32][8][4160]
static constexpr size_t OFF_MF   = OFF_MP   + 4259840;     // f32  [8][4160]
static constexpr size_t OFF_QT   = OFF_MF   + 133120;      // bf16 [4096][512]  (q̃)

__device__ __forceinline__ void gload16(const __hip_bfloat16* g, __hip_bfloat16* l) {
  __builtin_amdgcn_global_load_lds(
      (const __attribute__((address_space(1))) void*)g,
      (__attribute__((address_space(3))) void*)l, 16, 0, 0);
}

// XCD-bijective chunk swizzle (m204): contiguous grid chunks per XCD
__device__ __forceinline__ int xcd_swz(int orig, int nwg) {
  const int qq = nwg >> 3, rr = nwg & 7;
  const int xcd = orig & 7, off = orig >> 3;
  return (xcd < rr) ? (xcd * (qq + 1) + off)
                    : (rr * (qq + 1) + (xcd - rr) * qq + off);
}

// ---- batch fp32 [4096][1000] -> bf16 [4096][1024] (zero pad) --------------
__global__ void conv_pad_batch(const float* __restrict__ in, __hip_bfloat16* __restrict__ out) {
  int idx = blockIdx.x * 256 + threadIdx.x;
  int r = idx >> 10, c = idx & 1023;
  float v = (c < 1000) ? in[(size_t)r * 1000 + c] : 0.f;
  out[idx] = __float2bfloat16(v);
}

__global__ void concat3(const float* __restrict__ a, const float* __restrict__ b,
                        const float* __restrict__ c, float* __restrict__ out) {
  int i = blockIdx.x * 256 + threadIdx.x;
  if (i < 6144) {
    const float* src = (i < 2048) ? a : ((i < 4096) ? b : c);
    out[i] = src[i & 2047];
  }
}

// ---- W [K][N] fp32 -> Wt [Npad][Kpad] bf16, batched over z ----------------
__global__ void transpose_conv3(const float* __restrict__ s0, const float* __restrict__ s1,
                                const float* __restrict__ s2, __hip_bfloat16* __restrict__ outb,
                                size_t ostride, int K, int N, int Kpad) {
  const float* in = (blockIdx.z == 0) ? s0 : ((blockIdx.z == 1) ? s1 : s2);
  __hip_bfloat16* out = outb + (size_t)blockIdx.z * ostride;
  __shared__ float tile[32][33];
  int kb = blockIdx.x * 32, nb = blockIdx.y * 32;
  int tx = threadIdx.x, ty = threadIdx.y;            // block (32,8)
  for (int i = ty; i < 32; i += 8) {
    int k = kb + i, n = nb + tx;
    tile[i][tx] = (k < K && n < N) ? in[(size_t)k * N + n] : 0.f;
  }
  __syncthreads();
  for (int i = ty; i < 32; i += 8) {
    int n = nb + i, kp = kb + tx;
    out[(size_t)n * Kpad + kp] = __float2bfloat16(tile[tx][i]);
  }
}

// ---------------------------------------------------------------------------
// gemm_p8: 256x256 tile, BK=64, 8 waves, 8-phase schedule, counted vmcnt.
// ---------------------------------------------------------------------------
__global__ __launch_bounds__(512, 2) void gemm_p8(
    const __hip_bfloat16* __restrict__ A, int lda, size_t Az,
    const __hip_bfloat16* __restrict__ B, int ldb, size_t Bz,
    const float* __restrict__ bias0, const float* __restrict__ bias1,
    const float* __restrict__ bias2,
    __hip_bfloat16* __restrict__ Cout, int ldc, size_t Cz,
    int NT, int relu) {
  __shared__ __hip_bfloat16 sm[2][4][8192];          // [buf][A0,A1,B0,B1][128*64]
  const int t = threadIdx.x;
  const int z = blockIdx.z;
  const int gx = gridDim.x;
  const int id2 = xcd_swz(blockIdx.y * gx + blockIdx.x, gx * gridDim.y);
  const int m0 = (id2 / gx) * 256, n0 = (id2 % gx) * 256;
  A += (size_t)z * Az;
  B += (size_t)z * Bz;
  const float* bias = (z == 0) ? bias0 : ((z == 1) ? bias1 : bias2);

  const int w = t >> 6, l = t & 63;
  const int wm = w >> 2, wn = w & 3;
  const int fr = l & 15, fq = l >> 4;

  const int row0 = t >> 3, row1 = row0 + 64;
  const int c0 = (t & 7) ^ (row0 & 7);
  const int c1 = (t & 7) ^ (row1 & 7);
  const __hip_bfloat16* gA0a = A + (size_t)(m0 + row0) * lda + c0 * 8;
  const __hip_bfloat16* gA0b = A + (size_t)(m0 + row1) * lda + c1 * 8;
  const __hip_bfloat16* gA1a = gA0a + (size_t)128 * lda;
  const __hip_bfloat16* gA1b = gA0b + (size_t)128 * lda;
  const __hip_bfloat16* gB0a = B + (size_t)(n0 + row0) * ldb + c0 * 8;
  const __hip_bfloat16* gB0b = B + (size_t)(n0 + row1) * ldb + c1 * 8;
  const __hip_bfloat16* gB1a = gB0a + (size_t)128 * ldb;
  const __hip_bfloat16* gB1b = gB0b + (size_t)128 * ldb;

  const int baseA = (wm * 64 + fr) * 128;
  const int baseB = (wn * 32 + fr) * 128;
  const int xb0 = ((fq) ^ (fr & 7)) * 16;
  const int xb1 = ((4 + fq) ^ (fr & 7)) * 16;

  f32x4 acc[8][4] = {};
  bf16x8 af[4][2], bfv[2][2];

#define STG8(NXT, HALF, PA, PB, KT) do {                                       \
    gload16((PA) + (size_t)(KT) * 64, &sm[NXT][HALF][w * 512]);                \
    gload16((PB) + (size_t)(KT) * 64, &sm[NXT][HALF][w * 512 + 4096]);         \
  } while (0)

#define PH8(CUR, MG, NG, RDA, RDB, STG, WAITSTMT) do {                         \
    const char* a_ = (const char*)&sm[CUR][MG][0];                             \
    const char* b_ = (const char*)&sm[CUR][2 + (NG)][0];                       \
    if (RDA) {                                                                 \
      _Pragma("unroll") for (int i = 0; i < 4; ++i)                            \
        af[i][0] = *(const bf16x8*)(a_ + baseA + i * 2048 + xb0);              \
    }                                                                          \
    if (RDB) {                                                                 \
      _Pragma("unroll") for (int j = 0; j < 2; ++j)                            \
        bfv[j][0] = *(const bf16x8*)(b_ + baseB + j * 2048 + xb0);             \
    }                                                                          \
    if (RDA) {                                                                 \
      _Pragma("unroll") for (int i = 0; i < 4; ++i)                            \
        af[i][1] = *(const bf16x8*)(a_ + baseA + i * 2048 + xb1);              \
    }                                                                          \
    if (RDB) {                                                                 \
      _Pragma("unroll") for (int j = 0; j < 2; ++j)                            \
        bfv[j][1] = *(const bf16x8*)(b_ + baseB + j * 2048 + xb1);             \
    }                                                                          \
    STG;                                                                       \
    __builtin_amdgcn_s_barrier();                                              \
    __builtin_amdgcn_sched_barrier(0);                                         \
    __builtin_amdgcn_s_setprio(1);                                             \
    _Pragma("unroll") for (int ks = 0; ks < 2; ++ks)                           \
      _Pragma("unroll") for (int i = 0; i < 4; ++i)                            \
        _Pragma("unroll") for (int j = 0; j < 2; ++j)                          \
          acc[(MG) * 4 + i][(NG) * 2 + j] =                                    \
              __builtin_amdgcn_mfma_f32_16x16x32_bf16(                         \
                  af[i][ks], bfv[j][ks], acc[(MG) * 4 + i][(NG) * 2 + j],      \
                  0, 0, 0);                                                    \
    __builtin_amdgcn_s_setprio(0);                                             \
    WAITSTMT;                                                                  \
    __builtin_amdgcn_s_barrier();                                              \
  } while (0)

  // prologue: stage all 4 halves of tile 0 into buf 0, drain, barrier
  STG8(0, 0, gA0a, gA0b, 0);
  STG8(0, 1, gA1a, gA1b, 0);
  STG8(0, 2, gB0a, gB0b, 0);
  STG8(0, 3, gB1a, gB1b, 0);
  asm volatile("s_waitcnt vmcnt(0)" ::: "memory");
  __builtin_amdgcn_s_barrier();

  for (int T = 0; T < NT - 1; ++T) {
    const int cur = T & 1, nxt = cur ^ 1;
    const int kt = T + 1;
    PH8(cur, 0, 0, 1, 1, STG8(nxt, 0, gA0a, gA0b, kt), (void)0);
    PH8(cur, 1, 0, 1, 0, STG8(nxt, 1, gA1a, gA1b, kt),
        asm volatile("s_waitcnt vmcnt(4)" ::: "memory"));
    PH8(cur, 1, 1, 0, 1, STG8(nxt, 2, gB0a, gB0b, kt), (void)0);
    PH8(cur, 0, 1, 1, 0, STG8(nxt, 3, gB1a, gB1b, kt),
        asm volatile("s_waitcnt vmcnt(2)" ::: "memory"));
  }
  {
    const int cur = (NT - 1) & 1;
    PH8(cur, 0, 0, 1, 1, (void)0, (void)0);
    PH8(cur, 1, 0, 1, 0, (void)0,
        asm volatile("s_waitcnt vmcnt(0)" ::: "memory"));
    PH8(cur, 1, 1, 0, 1, (void)0, (void)0);
    PH8(cur, 0, 1, 1, 0, (void)0, (void)0);
  }
#undef PH8
#undef STG8

  // epilogue: quarter-split mapping
  __hip_bfloat16* C = Cout + (size_t)z * Cz;
  float bv[4];
#pragma unroll
  for (int nj = 0; nj < 4; ++nj) {
    const int col = n0 + (nj >> 1) * 128 + wn * 32 + (nj & 1) * 16 + fr;
    bv[nj] = bias[col];
  }
#pragma unroll
  for (int mi = 0; mi < 8; ++mi) {
    const int rowb = m0 + (mi >> 2) * 128 + wm * 64 + (mi & 3) * 16 + fq * 4;
#pragma unroll
    for (int nj = 0; nj < 4; ++nj) {
      const int col = n0 + (nj >> 1) * 128 + wn * 32 + (nj & 1) * 16 + fr;
#pragma unroll
      for (int rr = 0; rr < 4; ++rr) {
        float v = acc[mi][nj][rr] + bv[nj];
        if (relu) v = fmaxf(v, 0.f);
        C[(size_t)(rowb + rr) * ldc + col] = __float2bfloat16(v);
      }
    }
  }
}

// ---- generalized 128^2 m97-style GEMM (small shapes: G3, out-proj) --------
// epi: 0 = bf16, 1 = bf16+relu, 2 = f32 store guarded col<nlimit,
//      3 = bf16 + relu iff z<2
__global__ __launch_bounds__(256) void gemm_bt(
    const __hip_bfloat16* __restrict__ A, int lda, size_t Az,
    const __hip_bfloat16* __restrict__ B, int ldb, size_t Bz,
    const float* __restrict__ bias0, const float* __restrict__ bias1,
    const float* __restrict__ bias2,
    void* __restrict__ Cout, int ldc, size_t Cz,
    int nlimit, int K, int epi) {
  __shared__ __hip_bfloat16 As[128 * 32];
  __shared__ __hip_bfloat16 Bs[128 * 32];
  const int t = threadIdx.x;
  const int z = blockIdx.z;
  const int gx = gridDim.x;
  const int id2 = xcd_swz(blockIdx.y * gx + blockIdx.x, gx * gridDim.y);
  const int m0 = (id2 / gx) * 128, n0 = (id2 % gx) * 128;
  A += (size_t)z * Az;
  B += (size_t)z * Bz;
  const float* bias = (z == 0) ? bias0 : ((z == 1) ? bias1 : bias2);
  const int w = t >> 6, l = t & 63;
  const int wm = (w >> 1) * 64, wn = (w & 1) * 64;
  const int fr = l & 15, fq = l >> 4;
  const int sr = t >> 2, sc = (t & 3) * 8;

  f32x4 acc[4][4] = {};

  const __hip_bfloat16* ga = A + (size_t)(m0 + sr) * lda + sc;
  const __hip_bfloat16* gb = B + (size_t)(n0 + sr) * ldb + sc;
  __hip_bfloat16* la = As + w * 512;
  __hip_bfloat16* lb = Bs + w * 512;

  for (int k0 = 0; k0 < K; k0 += 32) {
    gload16(ga, la);
    gload16(ga + (size_t)64 * lda, la + 2048);
    gload16(gb, lb);
    gload16(gb + (size_t)64 * ldb, lb + 2048);
    ga += 32; gb += 32;
    __syncthreads();
    bf16x8 af[4], bfr[4];
#pragma unroll
    for (int i = 0; i < 4; ++i) {
      af[i]  = *reinterpret_cast<const bf16x8*>(&As[(wm + i * 16 + fr) * 32 + fq * 8]);
      bfr[i] = *reinterpret_cast<const bf16x8*>(&Bs[(wn + i * 16 + fr) * 32 + fq * 8]);
    }
#pragma unroll
    for (int i = 0; i < 4; ++i)
#pragma unroll
      for (int j = 0; j < 4; ++j)
        acc[i][j] = __builtin_amdgcn_mfma_f32_16x16x32_bf16(af[i], bfr[j], acc[i][j], 0, 0, 0);
    __syncthreads();
  }

  const bool dorelu = (epi == 1) || (epi == 3 && z < 2);
  float bv[4];
#pragma unroll
  for (int j = 0; j < 4; ++j) {
    int col = n0 + wn + j * 16 + fr;
    bv[j] = (col < nlimit) ? bias[col] : 0.f;
  }
#pragma unroll
  for (int i = 0; i < 4; ++i) {
#pragma unroll
    for (int j = 0; j < 4; ++j) {
      int col = n0 + wn + j * 16 + fr;
#pragma unroll
      for (int r = 0; r < 4; ++r) {
        int row = m0 + wm + i * 16 + fq * 4 + r;
        float v = acc[i][j][r] + bv[j];
        if (dorelu) v = fmaxf(v, 0.f);
        if (epi == 2) {
          if (col < nlimit)
            ((float*)Cout)[(size_t)row * ldc + col] = v;
        } else {
          ((__hip_bfloat16*)Cout + (size_t)z * Cz)[(size_t)row * ldc + col] = __float2bfloat16(v);
        }
      }
    }
  }
}

// ---- per-head partial M = kh^T vh (64x64) and ksum, over 128-row chunks ---
__global__ __launch_bounds__(256) void kv_outer(const __hip_bfloat16* __restrict__ QKV, int ld,
                                                float* __restrict__ part) {
  __shared__ __hip_bfloat16 kt[128][64];
  __shared__ __hip_bfloat16 vt[128][64];
  const int t = threadIdx.x;
  const int n0 = blockIdx.x * 128;
  const int h = blockIdx.y;
#pragma unroll
  for (int it = 0; it < 4; ++it) {
    int r = it * 32 + (t >> 3);
    int c = (t & 7) * 8;
    const __hip_bfloat16* kr = &QKV[(size_t)(n0 + r) * ld + 512 + h * 64 + c];
    const __hip_bfloat16* vr = &QKV[(size_t)(n0 + r) * ld + 1024 + h * 64 + c];
    *reinterpret_cast<bf16x8*>(&kt[r][c]) = *reinterpret_cast<const bf16x8*>(kr);
    *reinterpret_cast<bf16x8*>(&vt[r][c]) = *reinterpret_cast<const bf16x8*>(vr);
  }
  __syncthreads();
  const int i = t >> 2, j0 = (t & 3) << 4;
  float acc[16] = {};
  float ks = 0.f;
  for (int r = 0; r < 128; ++r) {
    float kv = __bfloat162float(kt[r][i]);
    ks += kv;
#pragma unroll
    for (int jj = 0; jj < 16; ++jj)
      acc[jj] += kv * __bfloat162float(vt[r][j0 + jj]);
  }
  float* dst = part + ((size_t)blockIdx.x * 8 + h) * 4160;
#pragma unroll
  for (int jj = 0; jj < 16; ++jj) dst[i * 64 + j0 + jj] = acc[jj];
  if ((t & 3) == 0) dst[4096 + i] = ks;
}

__global__ void reduce_m(const float* __restrict__ part, float* __restrict__ Mfin) {
  int h = blockIdx.x, t = threadIdx.x;
  for (int idx = t; idx < 4160; idx += 256) {
    float s = 0.f;
    for (int c = 0; c < 32; ++c) s += part[((size_t)c * 8 + h) * 4160 + idx];
    Mfin[(size_t)h * 4160 + idx] = s;
  }
}

// ---- MW^T[j][h*64+i] = sum_d M[h][i*64+d] * Wo[h*64+d][j]  (bf16 out) -----
// grid (4, 8 heads) x 256 threads. M_h staged in LDS (16 KB); each thread
// owns column j: wo column loaded coalesced ONCE into 64 registers, then
// 64x64 FMA with LDS broadcasts; 64 contiguous bf16 results -> 8x16B stores.
__global__ __launch_bounds__(256) void mw_kernel(const float* __restrict__ Mfin,
                                                 const float* __restrict__ wo,
                                                 __hip_bfloat16* __restrict__ MWT) {
  __shared__ float Ml[64][64];
  const int h = blockIdx.y;
  const int t = threadIdx.x;
  const int j = blockIdx.x * 256 + t;
  const float* M = Mfin + (size_t)h * 4160;
  for (int e = t; e < 4096; e += 256)
    Ml[e >> 6][e & 63] = M[e];
  __syncthreads();
  float wcol[64];
  const bool valid = (j < 1000);
#pragma unroll
  for (int d = 0; d < 64; ++d)
    wcol[d] = valid ? wo[(size_t)(h * 64 + d) * 1000 + j] : 0.f;
  short ob[64];
#pragma unroll
  for (int i = 0; i < 64; ++i) {
    float a = 0.f;
#pragma unroll
    for (int d = 0; d < 64; ++d) a += Ml[i][d] * wcol[d];
    __hip_bfloat16 b = __float2bfloat16(a);
    ob[i] = *(const short*)&b;
  }
  __hip_bfloat16* dst = MWT + (size_t)j * 512 + h * 64;
#pragma unroll
  for (int v = 0; v < 8; ++v)
    *reinterpret_cast<bf16x8*>(dst + v * 8) = *reinterpret_cast<const bf16x8*>(&ob[v * 8]);
}

// ---- q̃[n][h*64+:] = q̂ * 0.125 / den[n,h],  den = (q̂·ksum_h)/8 + 1e-8 ----
__global__ __launch_bounds__(256) void qscale(const __hip_bfloat16* __restrict__ QKV,
                                              const float* __restrict__ Mfin,
                                              __hip_bfloat16* __restrict__ QT) {
  const int t = threadIdx.x;
  const int r = blockIdx.x * 4 + (t >> 6);           // 1024 blocks, 4 rows each
  const int c = (t & 63) * 8;
  const int h = (t & 63) >> 3;
  bf16x8 qv = *reinterpret_cast<const bf16x8*>(&QKV[(size_t)r * 1536 + c]);
  float qf[8];
#pragma unroll
  for (int j = 0; j < 8; ++j)
    qf[j] = __bfloat162float(*(const __hip_bfloat16*)&((const short*)&qv)[j]);
  const float* ks = Mfin + (size_t)h * 4160 + 4096 + (c & 63);
  float s = 0.f;
#pragma unroll
  for (int j = 0; j < 8; ++j) s += qf[j] * ks[j];
  s += __shfl_xor(s, 1, 8);
  s += __shfl_xor(s, 2, 8);
  s += __shfl_xor(s, 4, 8);
  const float inv = 0.125f / (s * 0.125f + 1e-8f);
  bf16x8 o;
#pragma unroll
  for (int j = 0; j < 8; ++j) {
    __hip_bfloat16 b = __float2bfloat16(qf[j] * inv);
    ((short*)&o)[j] = *(const short*)&b;
  }
  *reinterpret_cast<bf16x8*>(&QT[(size_t)r * 512 + c]) = o;
}

// ---------------------------------------------------------------------------
extern "C" void kernel_launch(void* const* d_in, const int* in_sizes, int n_in,
                              void* d_out, int out_size, void* d_ws, size_t ws_size,
                              hipStream_t stream) {
  const float* batch = (const float*)d_in[0];
  const float* w1[3] = {(const float*)d_in[1],  (const float*)d_in[7],  (const float*)d_in[13]};
  const float* b1[3] = {(const float*)d_in[2],  (const float*)d_in[8],  (const float*)d_in[14]};
  const float* w2[3] = {(const float*)d_in[3],  (const float*)d_in[9],  (const float*)d_in[15]};
  const float* b2[3] = {(const float*)d_in[4],  (const float*)d_in[10], (const float*)d_in[16]};
  const float* w3[3] = {(const float*)d_in[5],  (const float*)d_in[11], (const float*)d_in[17]};
  const float* b3[3] = {(const float*)d_in[6],  (const float*)d_in[12], (const float*)d_in[18]};
  const float* wow   = (const float*)d_in[19];
  const float* wob   = (const float*)d_in[20];

  char* ws = (char*)d_ws;
  __hip_bfloat16* XB  = (__hip_bfloat16*)(ws + OFF_XB);
  __hip_bfloat16* WT1 = (__hip_bfloat16*)(ws + OFF_WT1);
  __hip_bfloat16* WT2 = (__hip_bfloat16*)(ws + OFF_WT2);
  __hip_bfloat16* WT3 = (__hip_bfloat16*)(ws + OFF_WT3);
  __hip_bfloat16* MWT = (__hip_bfloat16*)(ws + OFF_MWT);
  float*          B1C = (float*)(ws + OFF_B1C);
  __hip_bfloat16* H1  = (__hip_bfloat16*)(ws + OFF_H1);
  __hip_bfloat16* H2  = (__hip_bfloat16*)(ws + OFF_H2);
  __hip_bfloat16* QKV = (__hip_bfloat16*)(ws + OFF_QKV);
  float*          MP  = (float*)(ws + OFF_MP);
  float*          MF  = (float*)(ws + OFF_MF);
  __hip_bfloat16* QT  = (__hip_bfloat16*)(ws + OFF_QT);
  float*          OUT = (float*)d_out;

  // 1) input conversion / weight transposition (batched over z)
  conv_pad_batch<<<16384, 256, 0, stream>>>(batch, XB);
  concat3<<<24, 256, 0, stream>>>(b1[0], b1[1], b1[2], B1C);
  transpose_conv3<<<dim3(32, 64, 3), dim3(32, 8), 0, stream>>>(
      w1[0], w1[1], w1[2], WT1, (size_t)2048 * 1024, 1000, 2048, 1024);
  transpose_conv3<<<dim3(64, 32, 3), dim3(32, 8), 0, stream>>>(
      w2[0], w2[1], w2[2], WT2, (size_t)1024 * 2048, 2048, 1024, 2048);
  transpose_conv3<<<dim3(32, 16, 3), dim3(32, 8), 0, stream>>>(
      w3[0], w3[1], w3[2], WT3, (size_t)512 * 1024, 1024, 512, 1024);

  // 2) MLPs
  // G1 (merged q|k|v): [4096,1024] @ [1024,6144] -> H1 (relu)  [8-phase 256^2]
  gemm_p8<<<dim3(24, 16, 1), 512, 0, stream>>>(XB, 1024, 0, WT1, 1024, 0,
                                               B1C, B1C, B1C, H1, 6144, 0, 16, 1);
  // G2 z-batched: [4096,2048] @ [2048,1024] -> H2 (relu)       [8-phase 256^2]
  gemm_p8<<<dim3(4, 16, 3), 512, 0, stream>>>(H1, 6144, 2048, WT2, 2048, (size_t)1024 * 2048,
                                              b2[0], b2[1], b2[2], H2, 3072, 1024, 32, 1);
  // G3 z-batched: [4096,1024] @ [1024,512] -> QKV (q,k relu; v plain) [128^2]
  gemm_bt<<<dim3(4, 32, 3), 256, 0, stream>>>(H2, 3072, 1024, WT3, 1024, (size_t)512 * 1024,
                                              b3[0], b3[1], b3[2], QKV, 1536, 512,
                                              512, 1024, 3);

  // 3) attention reductions + fusion into out-proj operands
  kv_outer<<<dim3(32, 8), 256, 0, stream>>>(QKV, 1536, MP);
  reduce_m<<<8, 256, 0, stream>>>(MP, MF);
  mw_kernel<<<dim3(4, 8), 256, 0, stream>>>(MF, wow, MWT);
  qscale<<<1024, 256, 0, stream>>>(QKV, MF, QT);

  // 4) fused attention+output projection: q̃ @ MW^T -> d_out fp32 [128^2]
  gemm_bt<<<dim3(8, 32, 1), 256, 0, stream>>>(QT, 512, 0, MWT, 512, 0,
                                              wob, wob, wob, OUT, 1000, 0,
                                              1000, 512, 2);

  (void)in_sizes; (void)n_in; (void)out_size; (void)ws_size;
}

// Round 6
// 301.784 us; speedup vs baseline: 1.4433x; 1.0096x over previous
//
#include <hip/hip_runtime.h>
#include <hip/hip_bf16.h>

// ---------------------------------------------------------------------------
// MultiHeadAttention_21887153340754
// N=4096, IN=1000(pad 1024), H1=2048, H2=1024, EMB=512, HEADS=8, depth=64, OUT=1000
//
// Attention is LINEAR in scores (no softmax):
//   out = Σ_h (q̂_h/8/den) @ (M_h @ Wo_h) + b = q̃ @ MW + b,  M_h = k̂_h^T v_h
//
// Round 6:
//  (1) XCD RECTANGULAR clustering (replaces wrong strip swizzle that doubled
//      FETCH): hw assigns XCD = orig%8; map (xcd, slot) -> 2D tile rectangle
//      so each XCD's concurrent blocks share A/B panel slices in its L2.
//  (2) gemm_p8 phases rotated (0,0)->(0,1)->(1,1)->(1,0), both B halves kept
//      in registers: 24 ds_read_b128 per K-tile (minimum), new vmcnt ledger:
//      stages A0@phA,B0@phB,B1@phC,A1@phD; vmcnt(4) at A/B/D ends (>=3-phase
//      flight per load); last tile vmcnt(2)@A, vmcnt(0)@B.
// ---------------------------------------------------------------------------

typedef __attribute__((ext_vector_type(4))) float f32x4;
typedef __attribute__((ext_vector_type(8))) short bf16x8;

// ---- workspace layout (bytes) ---------------------------------------------
static constexpr size_t OFF_XB   = 0;                      // bf16 [4096][1024]
static constexpr size_t OFF_WT1  = OFF_XB   + 8388608;     // bf16 [6144][1024]
static constexpr size_t OFF_WT2  = OFF_WT1  + 12582912;    // bf16 [3][1024][2048]
static constexpr size_t OFF_WT3  = OFF_WT2  + 12582912;    // bf16 [3][512][1024]
static constexpr size_t OFF_MWT  = OFF_WT3  + 3145728;     // bf16 [1024][512]  (MW^T)
static constexpr size_t OFF_B1C  = OFF_MWT  + 1048576;     // f32  [6144]
static constexpr size_t OFF_H1   = OFF_B1C  + 24576;       // bf16 [4096][6144]
static constexpr size_t OFF_H2   = OFF_H1   + 50331648;    // bf16 [4096][3072]
static constexpr size_t OFF_QKV  = OFF_H2   + 25165824;    // bf16 [4096][1536]
static constexpr size_t OFF_MP   = OFF_QKV  + 12582912;    // f32  [32][8][4160]
static constexpr size_t OFF_MF   = OFF_MP   + 4259840;     // f32  [8][4160]
static constexpr size_t OFF_QT   = OFF_MF   + 133120;      // bf16 [4096][512]  (q̃)

__device__ __forceinline__ void gload16(const __hip_bfloat16* g, __hip_bfloat16* l) {
  __builtin_amdgcn_global_load_lds(
      (const __attribute__((address_space(1))) void*)g,
      (__attribute__((address_space(3))) void*)l, 16, 0, 0);
}

// XCD rectangular cluster map: hw XCD = idz%8 (round-robin). Give XCD a
// cm x cn tile rectangle; consecutive slots walk m first (share B-panel).
// Requires gy%cm==0, gx%cn==0, (gy/cm)*(gx/cn)==8, cm*cn==gx*gy/8.
__device__ __forceinline__ void xcd_rect(int idz, int gx, int cm, int cn,
                                         int& m, int& n) {
  const int xcd = idz & 7, slot = idz >> 3;
  const int nxr = gx / cn;                 // XCD columns in n-dir
  const int xr = xcd % nxr, yr = xcd / nxr;
  m = yr * cm + (slot % cm);
  n = xr * cn + (slot / cm);
}

// ---- batch fp32 [4096][1000] -> bf16 [4096][1024] (zero pad) --------------
__global__ void conv_pad_batch(const float* __restrict__ in, __hip_bfloat16* __restrict__ out) {
  int idx = blockIdx.x * 256 + threadIdx.x;
  int r = idx >> 10, c = idx & 1023;
  float v = (c < 1000) ? in[(size_t)r * 1000 + c] : 0.f;
  out[idx] = __float2bfloat16(v);
}

__global__ void concat3(const float* __restrict__ a, const float* __restrict__ b,
                        const float* __restrict__ c, float* __restrict__ out) {
  int i = blockIdx.x * 256 + threadIdx.x;
  if (i < 6144) {
    const float* src = (i < 2048) ? a : ((i < 4096) ? b : c);
    out[i] = src[i & 2047];
  }
}

// ---- W [K][N] fp32 -> Wt [Npad][Kpad] bf16, batched over z ----------------
__global__ void transpose_conv3(const float* __restrict__ s0, const float* __restrict__ s1,
                                const float* __restrict__ s2, __hip_bfloat16* __restrict__ outb,
                                size_t ostride, int K, int N, int Kpad) {
  const float* in = (blockIdx.z == 0) ? s0 : ((blockIdx.z == 1) ? s1 : s2);
  __hip_bfloat16* out = outb + (size_t)blockIdx.z * ostride;
  __shared__ float tile[32][33];
  int kb = blockIdx.x * 32, nb = blockIdx.y * 32;
  int tx = threadIdx.x, ty = threadIdx.y;            // block (32,8)
  for (int i = ty; i < 32; i += 8) {
    int k = kb + i, n = nb + tx;
    tile[i][tx] = (k < K && n < N) ? in[(size_t)k * N + n] : 0.f;
  }
  __syncthreads();
  for (int i = ty; i < 32; i += 8) {
    int n = nb + i, kp = kb + tx;
    out[(size_t)n * Kpad + kp] = __float2bfloat16(tile[tx][i]);
  }
}

// ---------------------------------------------------------------------------
// gemm_p8: 256x256 tile, BK=64, 8 waves, 8-phase, counted vmcnt, min ds_reads.
// ---------------------------------------------------------------------------
__global__ __launch_bounds__(512, 2) void gemm_p8(
    const __hip_bfloat16* __restrict__ A, int lda, size_t Az,
    const __hip_bfloat16* __restrict__ B, int ldb, size_t Bz,
    const float* __restrict__ bias0, const float* __restrict__ bias1,
    const float* __restrict__ bias2,
    __hip_bfloat16* __restrict__ Cout, int ldc, size_t Cz,
    int NT, int relu, int cm, int cn) {
  __shared__ __hip_bfloat16 sm[2][4][8192];          // [buf][A0,A1,B0,B1][128*64]
  const int t = threadIdx.x;
  const int z = blockIdx.z;
  int mt, nt;
  xcd_rect(blockIdx.y * gridDim.x + blockIdx.x, gridDim.x, cm, cn, mt, nt);
  const int m0 = mt * 256, n0 = nt * 256;
  A += (size_t)z * Az;
  B += (size_t)z * Bz;
  const float* bias = (z == 0) ? bias0 : ((z == 1) ? bias1 : bias2);

  const int w = t >> 6, l = t & 63;
  const int wm = w >> 2, wn = w & 3;
  const int fr = l & 15, fq = l >> 4;

  const int row0 = t >> 3, row1 = row0 + 64;
  const int c0 = (t & 7) ^ (row0 & 7);
  const int c1 = (t & 7) ^ (row1 & 7);
  const __hip_bfloat16* gA0a = A + (size_t)(m0 + row0) * lda + c0 * 8;
  const __hip_bfloat16* gA0b = A + (size_t)(m0 + row1) * lda + c1 * 8;
  const __hip_bfloat16* gA1a = gA0a + (size_t)128 * lda;
  const __hip_bfloat16* gA1b = gA0b + (size_t)128 * lda;
  const __hip_bfloat16* gB0a = B + (size_t)(n0 + row0) * ldb + c0 * 8;
  const __hip_bfloat16* gB0b = B + (size_t)(n0 + row1) * ldb + c1 * 8;
  const __hip_bfloat16* gB1a = gB0a + (size_t)128 * ldb;
  const __hip_bfloat16* gB1b = gB0b + (size_t)128 * ldb;

  const int baseA = (wm * 64 + fr) * 128;
  const int baseB = (wn * 32 + fr) * 128;
  const int xb0 = ((fq) ^ (fr & 7)) * 16;
  const int xb1 = ((4 + fq) ^ (fr & 7)) * 16;

  f32x4 acc[8][4] = {};
  bf16x8 af[4][2], bv0[2][2], bv1[2][2];

#define STG8(NXT, HALF, PA, PB, KT) do {                                       \
    gload16((PA) + (size_t)(KT) * 64, &sm[NXT][HALF][w * 512]);                \
    gload16((PB) + (size_t)(KT) * 64, &sm[NXT][HALF][w * 512 + 4096]);         \
  } while (0)

  // Phase: [ds_reads] [stage] [barrier] [MFMA] [wait] [barrier]
#define PHX(CUR, MG, NG, RDA, RDB0, RDB1, BARR, STG, WAITSTMT) do {            \
    const char* a_ = (const char*)&sm[CUR][MG][0];                             \
    const char* b_ = (const char*)&sm[CUR][2 + (NG)][0];                       \
    if (RDA) {                                                                 \
      _Pragma("unroll") for (int i = 0; i < 4; ++i)                            \
        af[i][0] = *(const bf16x8*)(a_ + baseA + i * 2048 + xb0);              \
      _Pragma("unroll") for (int i = 0; i < 4; ++i)                            \
        af[i][1] = *(const bf16x8*)(a_ + baseA + i * 2048 + xb1);              \
    }                                                                          \
    if (RDB0) {                                                                \
      _Pragma("unroll") for (int j = 0; j < 2; ++j) {                          \
        bv0[j][0] = *(const bf16x8*)(b_ + baseB + j * 2048 + xb0);             \
        bv0[j][1] = *(const bf16x8*)(b_ + baseB + j * 2048 + xb1);             \
      }                                                                        \
    }                                                                          \
    if (RDB1) {                                                                \
      _Pragma("unroll") for (int j = 0; j < 2; ++j) {                          \
        bv1[j][0] = *(const bf16x8*)(b_ + baseB + j * 2048 + xb0);             \
        bv1[j][1] = *(const bf16x8*)(b_ + baseB + j * 2048 + xb1);             \
      }                                                                        \
    }                                                                          \
    STG;                                                                       \
    __builtin_amdgcn_s_barrier();                                              \
    __builtin_amdgcn_sched_barrier(0);                                         \
    __builtin_amdgcn_s_setprio(1);                                             \
    _Pragma("unroll") for (int ks = 0; ks < 2; ++ks)                           \
      _Pragma("unroll") for (int i = 0; i < 4; ++i)                            \
        _Pragma("unroll") for (int j = 0; j < 2; ++j)                          \
          acc[(MG) * 4 + i][(NG) * 2 + j] =                                    \
              __builtin_amdgcn_mfma_f32_16x16x32_bf16(                         \
                  af[i][ks], BARR[j][ks], acc[(MG) * 4 + i][(NG) * 2 + j],     \
                  0, 0, 0);                                                    \
    __builtin_amdgcn_s_setprio(0);                                             \
    WAITSTMT;                                                                  \
    __builtin_amdgcn_s_barrier();                                              \
  } while (0)

  // prologue: stage all 4 halves of tile 0 into buf 0, drain, barrier
  STG8(0, 0, gA0a, gA0b, 0);
  STG8(0, 1, gA1a, gA1b, 0);
  STG8(0, 2, gB0a, gB0b, 0);
  STG8(0, 3, gB1a, gB1b, 0);
  asm volatile("s_waitcnt vmcnt(0)" ::: "memory");
  __builtin_amdgcn_s_barrier();

  // steady: stages A0@phA, B0@phB, B1@phC, A1@phD (FIFO); waits keep <=2
  // pairs outstanding exactly when the next phase's ds_reads need data.
  for (int T = 0; T < NT - 1; ++T) {
    const int cur = T & 1, nxt = cur ^ 1;
    const int kt = T + 1;
    PHX(cur, 0, 0, 1, 1, 0, bv0, STG8(nxt, 0, gA0a, gA0b, kt),
        asm volatile("s_waitcnt vmcnt(4)" ::: "memory"));
    PHX(cur, 0, 1, 0, 0, 1, bv1, STG8(nxt, 2, gB0a, gB0b, kt),
        asm volatile("s_waitcnt vmcnt(4)" ::: "memory"));
    PHX(cur, 1, 1, 1, 0, 0, bv1, STG8(nxt, 3, gB1a, gB1b, kt), (void)0);
    PHX(cur, 1, 0, 0, 0, 0, bv0, STG8(nxt, 1, gA1a, gA1b, kt),
        asm volatile("s_waitcnt vmcnt(4)" ::: "memory"));
  }
  {
    const int cur = (NT - 1) & 1;
    PHX(cur, 0, 0, 1, 1, 0, bv0, (void)0,
        asm volatile("s_waitcnt vmcnt(2)" ::: "memory"));
    PHX(cur, 0, 1, 0, 0, 1, bv1, (void)0,
        asm volatile("s_waitcnt vmcnt(0)" ::: "memory"));
    PHX(cur, 1, 1, 1, 0, 0, bv1, (void)0, (void)0);
    PHX(cur, 1, 0, 0, 0, 0, bv0, (void)0, (void)0);
  }
#undef PHX
#undef STG8

  // epilogue: quarter-split mapping
  __hip_bfloat16* C = Cout + (size_t)z * Cz;
  float bv[4];
#pragma unroll
  for (int nj = 0; nj < 4; ++nj) {
    const int col = n0 + (nj >> 1) * 128 + wn * 32 + (nj & 1) * 16 + fr;
    bv[nj] = bias[col];
  }
#pragma unroll
  for (int mi = 0; mi < 8; ++mi) {
    const int rowb = m0 + (mi >> 2) * 128 + wm * 64 + (mi & 3) * 16 + fq * 4;
#pragma unroll
    for (int nj = 0; nj < 4; ++nj) {
      const int col = n0 + (nj >> 1) * 128 + wn * 32 + (nj & 1) * 16 + fr;
#pragma unroll
      for (int rr = 0; rr < 4; ++rr) {
        float v = acc[mi][nj][rr] + bv[nj];
        if (relu) v = fmaxf(v, 0.f);
        C[(size_t)(rowb + rr) * ldc + col] = __float2bfloat16(v);
      }
    }
  }
}

// ---- generalized 128^2 m97-style GEMM (small shapes: G3, out-proj) --------
// epi: 0 = bf16, 1 = bf16+relu, 2 = f32 store guarded col<nlimit,
//      3 = bf16 + relu iff z<2
__global__ __launch_bounds__(256) void gemm_bt(
    const __hip_bfloat16* __restrict__ A, int lda, size_t Az,
    const __hip_bfloat16* __restrict__ B, int ldb, size_t Bz,
    const float* __restrict__ bias0, const float* __restrict__ bias1,
    const float* __restrict__ bias2,
    void* __restrict__ Cout, int ldc, size_t Cz,
    int nlimit, int K, int epi, int cm, int cn) {
  __shared__ __hip_bfloat16 As[128 * 32];
  __shared__ __hip_bfloat16 Bs[128 * 32];
  const int t = threadIdx.x;
  const int z = blockIdx.z;
  int mt, nt;
  xcd_rect(blockIdx.y * gridDim.x + blockIdx.x, gridDim.x, cm, cn, mt, nt);
  const int m0 = mt * 128, n0 = nt * 128;
  A += (size_t)z * Az;
  B += (size_t)z * Bz;
  const float* bias = (z == 0) ? bias0 : ((z == 1) ? bias1 : bias2);
  const int w = t >> 6, l = t & 63;
  const int wm = (w >> 1) * 64, wn = (w & 1) * 64;
  const int fr = l & 15, fq = l >> 4;
  const int sr = t >> 2, sc = (t & 3) * 8;

  f32x4 acc[4][4] = {};

  const __hip_bfloat16* ga = A + (size_t)(m0 + sr) * lda + sc;
  const __hip_bfloat16* gb = B + (size_t)(n0 + sr) * ldb + sc;
  __hip_bfloat16* la = As + w * 512;
  __hip_bfloat16* lb = Bs + w * 512;

  for (int k0 = 0; k0 < K; k0 += 32) {
    gload16(ga, la);
    gload16(ga + (size_t)64 * lda, la + 2048);
    gload16(gb, lb);
    gload16(gb + (size_t)64 * ldb, lb + 2048);
    ga += 32; gb += 32;
    __syncthreads();
    bf16x8 af[4], bfr[4];
#pragma unroll
    for (int i = 0; i < 4; ++i) {
      af[i]  = *reinterpret_cast<const bf16x8*>(&As[(wm + i * 16 + fr) * 32 + fq * 8]);
      bfr[i] = *reinterpret_cast<const bf16x8*>(&Bs[(wn + i * 16 + fr) * 32 + fq * 8]);
    }
#pragma unroll
    for (int i = 0; i < 4; ++i)
#pragma unroll
      for (int j = 0; j < 4; ++j)
        acc[i][j] = __builtin_amdgcn_mfma_f32_16x16x32_bf16(af[i], bfr[j], acc[i][j], 0, 0, 0);
    __syncthreads();
  }

  const bool dorelu = (epi == 1) || (epi == 3 && z < 2);
  float bv[4];
#pragma unroll
  for (int j = 0; j < 4; ++j) {
    int col = n0 + wn + j * 16 + fr;
    bv[j] = (col < nlimit) ? bias[col] : 0.f;
  }
#pragma unroll
  for (int i = 0; i < 4; ++i) {
#pragma unroll
    for (int j = 0; j < 4; ++j) {
      int col = n0 + wn + j * 16 + fr;
#pragma unroll
      for (int r = 0; r < 4; ++r) {
        int row = m0 + wm + i * 16 + fq * 4 + r;
        float v = acc[i][j][r] + bv[j];
        if (dorelu) v = fmaxf(v, 0.f);
        if (epi == 2) {
          if (col < nlimit)
            ((float*)Cout)[(size_t)row * ldc + col] = v;
        } else {
          ((__hip_bfloat16*)Cout + (size_t)z * Cz)[(size_t)row * ldc + col] = __float2bfloat16(v);
        }
      }
    }
  }
}

// ---- per-head partial M = kh^T vh (64x64) and ksum, over 128-row chunks ---
__global__ __launch_bounds__(256) void kv_outer(const __hip_bfloat16* __restrict__ QKV, int ld,
                                                float* __restrict__ part) {
  __shared__ __hip_bfloat16 kt[128][64];
  __shared__ __hip_bfloat16 vt[128][64];
  const int t = threadIdx.x;
  const int n0 = blockIdx.x * 128;
  const int h = blockIdx.y;
#pragma unroll
  for (int it = 0; it < 4; ++it) {
    int r = it * 32 + (t >> 3);
    int c = (t & 7) * 8;
    const __hip_bfloat16* kr = &QKV[(size_t)(n0 + r) * ld + 512 + h * 64 + c];
    const __hip_bfloat16* vr = &QKV[(size_t)(n0 + r) * ld + 1024 + h * 64 + c];
    *reinterpret_cast<bf16x8*>(&kt[r][c]) = *reinterpret_cast<const bf16x8*>(kr);
    *reinterpret_cast<bf16x8*>(&vt[r][c]) = *reinterpret_cast<const bf16x8*>(vr);
  }
  __syncthreads();
  const int i = t >> 2, j0 = (t & 3) << 4;
  float acc[16] = {};
  float ks = 0.f;
  for (int r = 0; r < 128; ++r) {
    float kv = __bfloat162float(kt[r][i]);
    ks += kv;
#pragma unroll
    for (int jj = 0; jj < 16; ++jj)
      acc[jj] += kv * __bfloat162float(vt[r][j0 + jj]);
  }
  float* dst = part + ((size_t)blockIdx.x * 8 + h) * 4160;
#pragma unroll
  for (int jj = 0; jj < 16; ++jj) dst[i * 64 + j0 + jj] = acc[jj];
  if ((t & 3) == 0) dst[4096 + i] = ks;
}

__global__ void reduce_m(const float* __restrict__ part, float* __restrict__ Mfin) {
  int h = blockIdx.x, t = threadIdx.x;
  for (int idx = t; idx < 4160; idx += 256) {
    float s = 0.f;
    for (int c = 0; c < 32; ++c) s += part[((size_t)c * 8 + h) * 4160 + idx];
    Mfin[(size_t)h * 4160 + idx] = s;
  }
}

// ---- MW^T[j][h*64+i] = sum_d M[h][i*64+d] * Wo[h*64+d][j]  (bf16 out) -----
__global__ __launch_bounds__(256) void mw_kernel(const float* __restrict__ Mfin,
                                                 const float* __restrict__ wo,
                                                 __hip_bfloat16* __restrict__ MWT) {
  __shared__ float Ml[64][64];
  const int h = blockIdx.y;
  const int t = threadIdx.x;
  const int j = blockIdx.x * 256 + t;
  const float* M = Mfin + (size_t)h * 4160;
  for (int e = t; e < 4096; e += 256)
    Ml[e >> 6][e & 63] = M[e];
  __syncthreads();
  float wcol[64];
  const bool valid = (j < 1000);
#pragma unroll
  for (int d = 0; d < 64; ++d)
    wcol[d] = valid ? wo[(size_t)(h * 64 + d) * 1000 + j] : 0.f;
  short ob[64];
#pragma unroll
  for (int i = 0; i < 64; ++i) {
    float a = 0.f;
#pragma unroll
    for (int d = 0; d < 64; ++d) a += Ml[i][d] * wcol[d];
    __hip_bfloat16 b = __float2bfloat16(a);
    ob[i] = *(const short*)&b;
  }
  __hip_bfloat16* dst = MWT + (size_t)j * 512 + h * 64;
#pragma unroll
  for (int v = 0; v < 8; ++v)
    *reinterpret_cast<bf16x8*>(dst + v * 8) = *reinterpret_cast<const bf16x8*>(&ob[v * 8]);
}

// ---- q̃[n][h*64+:] = q̂ * 0.125 / den[n,h],  den = (q̂·ksum_h)/8 + 1e-8 ----
__global__ __launch_bounds__(256) void qscale(const __hip_bfloat16* __restrict__ QKV,
                                              const float* __restrict__ Mfin,
                                              __hip_bfloat16* __restrict__ QT) {
  const int t = threadIdx.x;
  const int r = blockIdx.x * 4 + (t >> 6);           // 1024 blocks, 4 rows each
  const int c = (t & 63) * 8;
  const int h = (t & 63) >> 3;
  bf16x8 qv = *reinterpret_cast<const bf16x8*>(&QKV[(size_t)r * 1536 + c]);
  float qf[8];
#pragma unroll
  for (int j = 0; j < 8; ++j)
    qf[j] = __bfloat162float(*(const __hip_bfloat16*)&((const short*)&qv)[j]);
  const float* ks = Mfin + (size_t)h * 4160 + 4096 + (c & 63);
  float s = 0.f;
#pragma unroll
  for (int j = 0; j < 8; ++j) s += qf[j] * ks[j];
  s += __shfl_xor(s, 1, 8);
  s += __shfl_xor(s, 2, 8);
  s += __shfl_xor(s, 4, 8);
  const float inv = 0.125f / (s * 0.125f + 1e-8f);
  bf16x8 o;
#pragma unroll
  for (int j = 0; j < 8; ++j) {
    __hip_bfloat16 b = __float2bfloat16(qf[j] * inv);
    ((short*)&o)[j] = *(const short*)&b;
  }
  *reinterpret_cast<bf16x8*>(&QT[(size_t)r * 512 + c]) = o;
}

// ---------------------------------------------------------------------------
extern "C" void kernel_launch(void* const* d_in, const int* in_sizes, int n_in,
                              void* d_out, int out_size, void* d_ws, size_t ws_size,
                              hipStream_t stream) {
  const float* batch = (const float*)d_in[0];
  const float* w1[3] = {(const float*)d_in[1],  (const float*)d_in[7],  (const float*)d_in[13]};
  const float* b1[3] = {(const float*)d_in[2],  (const float*)d_in[8],  (const float*)d_in[14]};
  const float* w2[3] = {(const float*)d_in[3],  (const float*)d_in[9],  (const float*)d_in[15]};
  const float* b2[3] = {(const float*)d_in[4],  (const float*)d_in[10], (const float*)d_in[16]};
  const float* w3[3] = {(const float*)d_in[5],  (const float*)d_in[11], (const float*)d_in[17]};
  const float* b3[3] = {(const float*)d_in[6],  (const float*)d_in[12], (const float*)d_in[18]};
  const float* wow   = (const float*)d_in[19];
  const float* wob   = (const float*)d_in[20];

  char* ws = (char*)d_ws;
  __hip_bfloat16* XB  = (__hip_bfloat16*)(ws + OFF_XB);
  __hip_bfloat16* WT1 = (__hip_bfloat16*)(ws + OFF_WT1);
  __hip_bfloat16* WT2 = (__hip_bfloat16*)(ws + OFF_WT2);
  __hip_bfloat16* WT3 = (__hip_bfloat16*)(ws + OFF_WT3);
  __hip_bfloat16* MWT = (__hip_bfloat16*)(ws + OFF_MWT);
  float*          B1C = (float*)(ws + OFF_B1C);
  __hip_bfloat16* H1  = (__hip_bfloat16*)(ws + OFF_H1);
  __hip_bfloat16* H2  = (__hip_bfloat16*)(ws + OFF_H2);
  __hip_bfloat16* QKV = (__hip_bfloat16*)(ws + OFF_QKV);
  float*          MP  = (float*)(ws + OFF_MP);
  float*          MF  = (float*)(ws + OFF_MF);
  __hip_bfloat16* QT  = (__hip_bfloat16*)(ws + OFF_QT);
  float*          OUT = (float*)d_out;

  // 1) input conversion / weight transposition (batched over z)
  conv_pad_batch<<<16384, 256, 0, stream>>>(batch, XB);
  concat3<<<24, 256, 0, stream>>>(b1[0], b1[1], b1[2], B1C);
  transpose_conv3<<<dim3(32, 64, 3), dim3(32, 8), 0, stream>>>(
      w1[0], w1[1], w1[2], WT1, (size_t)2048 * 1024, 1000, 2048, 1024);
  transpose_conv3<<<dim3(64, 32, 3), dim3(32, 8), 0, stream>>>(
      w2[0], w2[1], w2[2], WT2, (size_t)1024 * 2048, 2048, 1024, 2048);
  transpose_conv3<<<dim3(32, 16, 3), dim3(32, 8), 0, stream>>>(
      w3[0], w3[1], w3[2], WT3, (size_t)512 * 1024, 1024, 512, 1024);

  // 2) MLPs
  // G1: [4096,1024]@[1024,6144] -> H1 (relu). grid 24x16 -> clusters 8m x 6n
  gemm_p8<<<dim3(24, 16, 1), 512, 0, stream>>>(XB, 1024, 0, WT1, 1024, 0,
                                               B1C, B1C, B1C, H1, 6144, 0, 16, 1, 8, 6);
  // G2 z-batched: [4096,2048]@[2048,1024] -> H2 (relu). per-z 4x16 -> 4m x 2n
  gemm_p8<<<dim3(4, 16, 3), 512, 0, stream>>>(H1, 6144, 2048, WT2, 2048, (size_t)1024 * 2048,
                                              b2[0], b2[1], b2[2], H2, 3072, 1024, 32, 1, 4, 2);
  // G3 z-batched: [4096,1024]@[1024,512] -> QKV. per-z 4x32 -> 8m x 2n
  gemm_bt<<<dim3(4, 32, 3), 256, 0, stream>>>(H2, 3072, 1024, WT3, 1024, (size_t)512 * 1024,
                                              b3[0], b3[1], b3[2], QKV, 1536, 512,
                                              512, 1024, 3, 8, 2);

  // 3) attention reductions + fusion into out-proj operands
  kv_outer<<<dim3(32, 8), 256, 0, stream>>>(QKV, 1536, MP);
  reduce_m<<<8, 256, 0, stream>>>(MP, MF);
  mw_kernel<<<dim3(4, 8), 256, 0, stream>>>(MF, wow, MWT);
  qscale<<<1024, 256, 0, stream>>>(QKV, MF, QT);

  // 4) fused attention+output projection: q̃ @ MW^T -> d_out fp32. 8x32 -> 8m x 4n
  gemm_bt<<<dim3(8, 32, 1), 256, 0, stream>>>(QT, 512, 0, MWT, 512, 0,
                                              wob, wob, wob, OUT, 1000, 0,
                                              1000, 512, 2, 8, 4);

  (void)in_sizes; (void)n_in; (void)out_size; (void)ws_size;
}

// Round 7
// 295.717 us; speedup vs baseline: 1.4729x; 1.0205x over previous
//
#include <hip/hip_runtime.h>
#include <hip/hip_bf16.h>

// ---------------------------------------------------------------------------
// MultiHeadAttention_21887153340754
// N=4096, IN=1000(pad 1024), H1=2048, H2=1024, EMB=512, HEADS=8, depth=64, OUT=1000
//
// Attention is LINEAR in scores (no softmax):
//   out = Σ_h (q̂_h/8/den) @ (M_h @ Wo_h) + b = q̃ @ MW + b,  M_h = k̂_h^T v_h
//
// Round 7:
//  (1) gemm_pp: 256² tile, BK=32, LDS 64KB -> 2 blocks/CU co-resident
//      (round-6 was 128KB -> 1 block/CU, Occupancy 15%, barrier dead time
//      unhideable). ONE barrier + ONE waitcnt per K-tile; cross-block overlap
//      hides the vmcnt(0) stall (m114 mechanism). BK=32 swizzle:
//      slot = fq ^ ((row>>1)&3) -> conflict-free ds_read_b128.
//  (2) 13 -> 8 kernel launches: mega-prep (9 transposes + batch pad),
//      concat3 deleted (bias col-select in G1 epilogue), mw+qscale fused.
//  (3) kv_outer inner loop vectorized (2x b128 instead of 16 scalar reads).
// ---------------------------------------------------------------------------

typedef __attribute__((ext_vector_type(4))) float f32x4;
typedef __attribute__((ext_vector_type(4))) float float4v;
typedef __attribute__((ext_vector_type(8))) short bf16x8;

// ---- workspace layout (bytes) ---------------------------------------------
static constexpr size_t OFF_XB   = 0;                      // bf16 [4096][1024]
static constexpr size_t OFF_WT1  = OFF_XB   + 8388608;     // bf16 [3][2048][1024]
static constexpr size_t OFF_WT2  = OFF_WT1  + 12582912;    // bf16 [3][1024][2048]
static constexpr size_t OFF_WT3  = OFF_WT2  + 12582912;    // bf16 [3][512][1024]
static constexpr size_t OFF_MWT  = OFF_WT3  + 3145728;     // bf16 [1024][512]  (MW^T)
static constexpr size_t OFF_B1C  = OFF_MWT  + 1048576;     // (unused hole)
static constexpr size_t OFF_H1   = OFF_B1C  + 24576;       // bf16 [4096][6144]
static constexpr size_t OFF_H2   = OFF_H1   + 50331648;    // bf16 [4096][3072]
static constexpr size_t OFF_QKV  = OFF_H2   + 25165824;    // bf16 [4096][1536]
static constexpr size_t OFF_MP   = OFF_QKV  + 12582912;    // f32  [32][8][4160]
static constexpr size_t OFF_MF   = OFF_MP   + 4259840;     // f32  [8][4160]
static constexpr size_t OFF_QT   = OFF_MF   + 133120;      // bf16 [4096][512]  (q̃)

__device__ __forceinline__ void gload16(const __hip_bfloat16* g, __hip_bfloat16* l) {
  __builtin_amdgcn_global_load_lds(
      (const __attribute__((address_space(1))) void*)g,
      (__attribute__((address_space(3))) void*)l, 16, 0, 0);
}

// XCD rectangular cluster map: hw XCD = idz%8 (round-robin). Give XCD a
// cm x cn tile rectangle; consecutive slots walk m first (share B-panel).
__device__ __forceinline__ void xcd_rect(int idz, int gx, int cm, int cn,
                                         int& m, int& n) {
  const int xcd = idz & 7, slot = idz >> 3;
  const int nxr = gx / cn;                 // XCD columns in n-dir
  const int xr = xcd % nxr, yr = xcd / nxr;
  m = yr * cm + (slot % cm);
  n = xr * cn + (slot / cm);
}

// ---- mega-prep: 9 weight transposes (fp32 [K][N] -> bf16 [N][Kpad]) + batch
// pad/convert. Block = 256 threads. Blocks:
//   [0,6144)      w1 p=b/2048:  K=1000 N=2048 Kpad=1024, tiles 32k x 64n
//   [6144,12288)  w2:           K=2048 N=1024 Kpad=2048, tiles 64k x 32n
//   [12288,13824) w3:           K=1024 N=512  Kpad=1024, tiles 32k x 16n
//   [13824,17920) conv: batch fp32 [4096][1000] -> bf16 [4096][1024]
__global__ __launch_bounds__(256) void prep(
    const float* __restrict__ w1a, const float* __restrict__ w1b, const float* __restrict__ w1c,
    const float* __restrict__ w2a, const float* __restrict__ w2b, const float* __restrict__ w2c,
    const float* __restrict__ w3a, const float* __restrict__ w3b, const float* __restrict__ w3c,
    const float* __restrict__ batch,
    __hip_bfloat16* __restrict__ WT1, __hip_bfloat16* __restrict__ WT2,
    __hip_bfloat16* __restrict__ WT3, __hip_bfloat16* __restrict__ XB) {
  __shared__ float tile[32][33];
  const int b = blockIdx.x, t = threadIdx.x;
  if (b >= 13824) {                                  // conv region
    int idx = (b - 13824) * 256 + t;                 // 4096x256 threads
    int row = idx >> 8, c4 = (idx & 255) * 4;
    __hip_bfloat16 o[4];
    if (c4 < 1000) {
      float4v v = *reinterpret_cast<const float4v*>(&batch[(size_t)row * 1000 + c4]);
#pragma unroll
      for (int j = 0; j < 4; ++j) o[j] = __float2bfloat16(v[j]);
    } else {
#pragma unroll
      for (int j = 0; j < 4; ++j) o[j] = __float2bfloat16(0.f);
    }
    *reinterpret_cast<ushort4*>(&XB[(size_t)row * 1024 + c4]) =
        *reinterpret_cast<const ushort4*>(o);
    return;
  }
  const float* in; __hip_bfloat16* out; int K, N, Kpad, kb, nb;
  if (b < 6144) {
    int mat = b >> 11, r = b & 2047;
    const float* s[3] = {w1a, w1b, w1c};
    in = s[mat]; out = WT1 + (size_t)mat * 2048 * 1024;
    K = 1000; N = 2048; Kpad = 1024; kb = r & 31; nb = r >> 5;
  } else if (b < 12288) {
    int r = b - 6144; int mat = r >> 11; r &= 2047;
    const float* s[3] = {w2a, w2b, w2c};
    in = s[mat]; out = WT2 + (size_t)mat * 1024 * 2048;
    K = 2048; N = 1024; Kpad = 2048; kb = r & 63; nb = r >> 6;
  } else {
    int r = b - 12288; int mat = r >> 9; r &= 511;
    const float* s[3] = {w3a, w3b, w3c};
    in = s[mat]; out = WT3 + (size_t)mat * 512 * 1024;
    K = 1024; N = 512; Kpad = 1024; kb = r & 31; nb = r >> 5;
  }
  const int tx = t & 31, ty = t >> 5;
  const int kb32 = kb * 32, nb32 = nb * 32;
  for (int i = ty; i < 32; i += 8) {
    int k = kb32 + i, n = nb32 + tx;
    tile[i][tx] = (k < K && n < N) ? in[(size_t)k * N + n] : 0.f;
  }
  __syncthreads();
  for (int i = ty; i < 32; i += 8) {
    int n = nb32 + i, kp = kb32 + tx;
    out[(size_t)n * Kpad + kp] = __float2bfloat16(tile[tx][i]);
  }
}

// ---------------------------------------------------------------------------
// gemm_pp: 256x256 tile, BK=32, 8 waves (2M x 4N quarter-split), LDS 64KB
// (2 blocks/CU). Per K-tile: [wait vmcnt(0) lgkm(0); barrier] -> 12 ds_read
// -> 4 global_load_lds (tile T+1) -> 32 MFMA. One barrier per K-tile.
// Swizzle (64B rows, 4x16B slots): slot = colgroup ^ ((row>>1)&3).
// mode: 1 = bias selected by col>>11 from {bias0,bias1,bias2} (G1 merged),
//       0 = bias selected by blockIdx.z (G2). ReLU always.
// ---------------------------------------------------------------------------
__global__ __launch_bounds__(512, 2) void gemm_pp(
    const __hip_bfloat16* __restrict__ A, int lda, size_t Az,
    const __hip_bfloat16* __restrict__ B, int ldb, size_t Bz,
    const float* __restrict__ bias0, const float* __restrict__ bias1,
    const float* __restrict__ bias2,
    __hip_bfloat16* __restrict__ Cout, int ldc, size_t Cz,
    int NT, int mode, int cm, int cn) {
  __shared__ __hip_bfloat16 smA[2][8192];            // [buf][256 rows x 32]
  __shared__ __hip_bfloat16 smB[2][8192];
  const int t = threadIdx.x;
  const int z = blockIdx.z;
  int mt, nt;
  xcd_rect(blockIdx.y * gridDim.x + blockIdx.x, gridDim.x, cm, cn, mt, nt);
  const int m0 = mt * 256, n0 = nt * 256;
  A += (size_t)z * Az;
  B += (size_t)z * Bz;

  const int w = t >> 6, l = t & 63;
  const int wm = w >> 2, wn = w & 3;
  const int fr = l & 15, fq = l >> 4;

  // staging: thread t covers LDS bytes t*16 (+8192 for rows 128..255).
  // linear byte L: row = L>>6, slot = (L>>4)&3, colgroup = slot ^ ((row>>1)&3)
  const int r0 = t >> 2;
  const int cg = (t & 3) ^ ((t >> 3) & 3);
  const __hip_bfloat16* gA0 = A + (size_t)(m0 + r0) * lda + cg * 8;
  const __hip_bfloat16* gA1 = A + (size_t)(m0 + 128 + r0) * lda + cg * 8;
  const __hip_bfloat16* gB0 = B + (size_t)(n0 + r0) * ldb + cg * 8;
  const __hip_bfloat16* gB1 = B + (size_t)(n0 + 128 + r0) * ldb + cg * 8;

  // ds_read element offsets: row*32 + (fq ^ ((row>>1)&3))*8 ; (row>>1)&3 = (fr>>1)&3
  const int soff = (fq ^ ((fr >> 1) & 3)) * 8;
  int offA[4], offB[2][2];
#pragma unroll
  for (int i = 0; i < 4; ++i) offA[i] = (wm * 64 + i * 16 + fr) * 32 + soff;
#pragma unroll
  for (int ng = 0; ng < 2; ++ng)
#pragma unroll
    for (int j = 0; j < 2; ++j)
      offB[ng][j] = (ng * 128 + wn * 32 + j * 16 + fr) * 32 + soff;

  f32x4 acc[8][4] = {};

  // prologue: stage tile 0 into buf 0
  gload16(gA0, &smA[0][w * 512]);
  gload16(gA1, &smA[0][w * 512 + 4096]);
  gload16(gB0, &smB[0][w * 512]);
  gload16(gB1, &smB[0][w * 512 + 4096]);
  asm volatile("s_waitcnt vmcnt(0)" ::: "memory");
  __builtin_amdgcn_s_barrier();

  for (int T = 0; T < NT; ++T) {
    const int cur = T & 1, nxt = cur ^ 1;
    if (T > 0) {
      // drain: prev tile's reads (lgkm) so STG below may overwrite their
      // buffer; prev-issued stages (vmcnt) so ds_reads below see data.
      asm volatile("s_waitcnt vmcnt(0) lgkmcnt(0)" ::: "memory");
      __builtin_amdgcn_sched_barrier(0);
      __builtin_amdgcn_s_barrier();
    }
    bf16x8 af0[4], af1[4], bfv[2][2];
#pragma unroll
    for (int i = 0; i < 4; ++i) {
      af0[i] = *reinterpret_cast<const bf16x8*>(&smA[cur][offA[i]]);
      af1[i] = *reinterpret_cast<const bf16x8*>(&smA[cur][offA[i] + 4096]);
    }
#pragma unroll
    for (int ng = 0; ng < 2; ++ng)
#pragma unroll
      for (int j = 0; j < 2; ++j)
        bfv[ng][j] = *reinterpret_cast<const bf16x8*>(&smB[cur][offB[ng][j]]);
    if (T + 1 < NT) {
      const size_t ko = (size_t)(T + 1) * 32;
      gload16(gA0 + ko, &smA[nxt][w * 512]);
      gload16(gA1 + ko, &smA[nxt][w * 512 + 4096]);
      gload16(gB0 + ko, &smB[nxt][w * 512]);
      gload16(gB1 + ko, &smB[nxt][w * 512 + 4096]);
    }
    __builtin_amdgcn_s_setprio(1);
#pragma unroll
    for (int i = 0; i < 4; ++i)
#pragma unroll
      for (int ng = 0; ng < 2; ++ng)
#pragma unroll
        for (int j = 0; j < 2; ++j)
          acc[i][ng * 2 + j] = __builtin_amdgcn_mfma_f32_16x16x32_bf16(
              af0[i], bfv[ng][j], acc[i][ng * 2 + j], 0, 0, 0);
#pragma unroll
    for (int i = 0; i < 4; ++i)
#pragma unroll
      for (int ng = 0; ng < 2; ++ng)
#pragma unroll
        for (int j = 0; j < 2; ++j)
          acc[4 + i][ng * 2 + j] = __builtin_amdgcn_mfma_f32_16x16x32_bf16(
              af1[i], bfv[ng][j], acc[4 + i][ng * 2 + j], 0, 0, 0);
    __builtin_amdgcn_s_setprio(0);
  }

  // epilogue: quarter-split mapping; bias per mode; relu
  __hip_bfloat16* C = Cout + (size_t)z * Cz;
  const float* bz = (z == 0) ? bias0 : ((z == 1) ? bias1 : bias2);
  float bvv[4];
#pragma unroll
  for (int nj = 0; nj < 4; ++nj) {
    const int col = n0 + (nj >> 1) * 128 + wn * 32 + (nj & 1) * 16 + fr;
    if (mode == 1) {
      const float* bsel = (col < 2048) ? bias0 : ((col < 4096) ? bias1 : bias2);
      bvv[nj] = bsel[col & 2047];
    } else {
      bvv[nj] = bz[col];
    }
  }
#pragma unroll
  for (int mi = 0; mi < 8; ++mi) {
    const int rowb = m0 + (mi >> 2) * 128 + wm * 64 + (mi & 3) * 16 + fq * 4;
#pragma unroll
    for (int nj = 0; nj < 4; ++nj) {
      const int col = n0 + (nj >> 1) * 128 + wn * 32 + (nj & 1) * 16 + fr;
#pragma unroll
      for (int rr = 0; rr < 4; ++rr) {
        float v = fmaxf(acc[mi][nj][rr] + bvv[nj], 0.f);
        C[(size_t)(rowb + rr) * ldc + col] = __float2bfloat16(v);
      }
    }
  }
}

// ---- generalized 128^2 m97-style GEMM (small shapes: G3, out-proj) --------
// epi: 2 = f32 store guarded col<nlimit, 3 = bf16 + relu iff z<2
__global__ __launch_bounds__(256) void gemm_bt(
    const __hip_bfloat16* __restrict__ A, int lda, size_t Az,
    const __hip_bfloat16* __restrict__ B, int ldb, size_t Bz,
    const float* __restrict__ bias0, const float* __restrict__ bias1,
    const float* __restrict__ bias2,
    void* __restrict__ Cout, int ldc, size_t Cz,
    int nlimit, int K, int epi, int cm, int cn) {
  __shared__ __hip_bfloat16 As[128 * 32];
  __shared__ __hip_bfloat16 Bs[128 * 32];
  const int t = threadIdx.x;
  const int z = blockIdx.z;
  int mt, nt;
  xcd_rect(blockIdx.y * gridDim.x + blockIdx.x, gridDim.x, cm, cn, mt, nt);
  const int m0 = mt * 128, n0 = nt * 128;
  A += (size_t)z * Az;
  B += (size_t)z * Bz;
  const float* bias = (z == 0) ? bias0 : ((z == 1) ? bias1 : bias2);
  const int w = t >> 6, l = t & 63;
  const int wm = (w >> 1) * 64, wn = (w & 1) * 64;
  const int fr = l & 15, fq = l >> 4;
  const int sr = t >> 2, sc = (t & 3) * 8;

  f32x4 acc[4][4] = {};

  const __hip_bfloat16* ga = A + (size_t)(m0 + sr) * lda + sc;
  const __hip_bfloat16* gb = B + (size_t)(n0 + sr) * ldb + sc;
  __hip_bfloat16* la = As + w * 512;
  __hip_bfloat16* lb = Bs + w * 512;

  for (int k0 = 0; k0 < K; k0 += 32) {
    gload16(ga, la);
    gload16(ga + (size_t)64 * lda, la + 2048);
    gload16(gb, lb);
    gload16(gb + (size_t)64 * ldb, lb + 2048);
    ga += 32; gb += 32;
    __syncthreads();
    bf16x8 af[4], bfr[4];
#pragma unroll
    for (int i = 0; i < 4; ++i) {
      af[i]  = *reinterpret_cast<const bf16x8*>(&As[(wm + i * 16 + fr) * 32 + fq * 8]);
      bfr[i] = *reinterpret_cast<const bf16x8*>(&Bs[(wn + i * 16 + fr) * 32 + fq * 8]);
    }
#pragma unroll
    for (int i = 0; i < 4; ++i)
#pragma unroll
      for (int j = 0; j < 4; ++j)
        acc[i][j] = __builtin_amdgcn_mfma_f32_16x16x32_bf16(af[i], bfr[j], acc[i][j], 0, 0, 0);
    __syncthreads();
  }

  const bool dorelu = (epi == 3 && z < 2);
  float bv[4];
#pragma unroll
  for (int j = 0; j < 4; ++j) {
    int col = n0 + wn + j * 16 + fr;
    bv[j] = (col < nlimit) ? bias[col] : 0.f;
  }
#pragma unroll
  for (int i = 0; i < 4; ++i) {
#pragma unroll
    for (int j = 0; j < 4; ++j) {
      int col = n0 + wn + j * 16 + fr;
#pragma unroll
      for (int r = 0; r < 4; ++r) {
        int row = m0 + wm + i * 16 + fq * 4 + r;
        float v = acc[i][j][r] + bv[j];
        if (dorelu) v = fmaxf(v, 0.f);
        if (epi == 2) {
          if (col < nlimit)
            ((float*)Cout)[(size_t)row * ldc + col] = v;
        } else {
          ((__hip_bfloat16*)Cout + (size_t)z * Cz)[(size_t)row * ldc + col] = __float2bfloat16(v);
        }
      }
    }
  }
}

// ---- per-head partial M = kh^T vh (64x64) and ksum, over 128-row chunks ---
__global__ __launch_bounds__(256) void kv_outer(const __hip_bfloat16* __restrict__ QKV, int ld,
                                                float* __restrict__ part) {
  __shared__ __hip_bfloat16 kt[128][64];
  __shared__ __hip_bfloat16 vt[128][64];
  const int t = threadIdx.x;
  const int n0 = blockIdx.x * 128;
  const int h = blockIdx.y;
#pragma unroll
  for (int it = 0; it < 4; ++it) {
    int r = it * 32 + (t >> 3);
    int c = (t & 7) * 8;
    const __hip_bfloat16* kr = &QKV[(size_t)(n0 + r) * ld + 512 + h * 64 + c];
    const __hip_bfloat16* vr = &QKV[(size_t)(n0 + r) * ld + 1024 + h * 64 + c];
    *reinterpret_cast<bf16x8*>(&kt[r][c]) = *reinterpret_cast<const bf16x8*>(kr);
    *reinterpret_cast<bf16x8*>(&vt[r][c]) = *reinterpret_cast<const bf16x8*>(vr);
  }
  __syncthreads();
  const int i = t >> 2, j0 = (t & 3) << 4;
  float acc[16] = {};
  float ks = 0.f;
  for (int r = 0; r < 128; ++r) {
    float kv = __bfloat162float(kt[r][i]);
    ks += kv;
    bf16x8 va = *reinterpret_cast<const bf16x8*>(&vt[r][j0]);
    bf16x8 vb = *reinterpret_cast<const bf16x8*>(&vt[r][j0 + 8]);
#pragma unroll
    for (int jj = 0; jj < 8; ++jj) {
      ushort ua = (ushort)((const short*)&va)[jj];
      ushort ub = (ushort)((const short*)&vb)[jj];
      acc[jj]     += kv * __bfloat162float(*(const __hip_bfloat16*)&ua);
      acc[8 + jj] += kv * __bfloat162float(*(const __hip_bfloat16*)&ub);
    }
  }
  float* dst = part + ((size_t)blockIdx.x * 8 + h) * 4160;
#pragma unroll
  for (int jj = 0; jj < 16; ++jj) dst[i * 64 + j0 + jj] = acc[jj];
  if ((t & 3) == 0) dst[4096 + i] = ks;
}

__global__ void reduce_m(const float* __restrict__ part, float* __restrict__ Mfin) {
  int h = blockIdx.x, t = threadIdx.x;
  for (int idx = t; idx < 4160; idx += 256) {
    float s = 0.f;
    for (int c = 0; c < 32; ++c) s += part[((size_t)c * 8 + h) * 4160 + idx];
    Mfin[(size_t)h * 4160 + idx] = s;
  }
}

// ---- fused: blocks [0,32): MW^T = M_h @ Wo_h (bf16); [32,1056): q̃ --------
__global__ __launch_bounds__(256) void mwq(const float* __restrict__ Mfin,
                                           const float* __restrict__ wo,
                                           __hip_bfloat16* __restrict__ MWT,
                                           const __hip_bfloat16* __restrict__ QKV,
                                           __hip_bfloat16* __restrict__ QT) {
  const int t = threadIdx.x;
  if (blockIdx.x < 32) {
    // MW^T[j][h*64+i] = sum_d M[h][i*64+d] * wo[(h*64+d)*1000 + j]
    __shared__ float Ml[64][64];
    const int h = blockIdx.x >> 2;
    const int j = (blockIdx.x & 3) * 256 + t;
    const float* M = Mfin + (size_t)h * 4160;
    for (int e = t; e < 4096; e += 256)
      Ml[e >> 6][e & 63] = M[e];
    __syncthreads();
    float wcol[64];
    const bool valid = (j < 1000);
#pragma unroll
    for (int d = 0; d < 64; ++d)
      wcol[d] = valid ? wo[(size_t)(h * 64 + d) * 1000 + j] : 0.f;
    short ob[64];
#pragma unroll
    for (int i = 0; i < 64; ++i) {
      float a = 0.f;
#pragma unroll
      for (int d = 0; d < 64; ++d) a += Ml[i][d] * wcol[d];
      __hip_bfloat16 bb = __float2bfloat16(a);
      ob[i] = *(const short*)&bb;
    }
    __hip_bfloat16* dst = MWT + (size_t)j * 512 + h * 64;
#pragma unroll
    for (int v = 0; v < 8; ++v)
      *reinterpret_cast<bf16x8*>(dst + v * 8) = *reinterpret_cast<const bf16x8*>(&ob[v * 8]);
  } else {
    // q̃[n] = q̂ * 0.125 / den,  den = (q̂·ksum_h)/8 + 1e-8
    const int bid = blockIdx.x - 32;
    const int r = bid * 4 + (t >> 6);
    const int c = (t & 63) * 8;
    const int h = (t & 63) >> 3;
    bf16x8 qv = *reinterpret_cast<const bf16x8*>(&QKV[(size_t)r * 1536 + c]);
    float qf[8];
#pragma unroll
    for (int j = 0; j < 8; ++j) {
      ushort u = (ushort)((const short*)&qv)[j];
      qf[j] = __bfloat162float(*(const __hip_bfloat16*)&u);
    }
    const float* ks = Mfin + (size_t)h * 4160 + 4096 + (c & 63);
    float s = 0.f;
#pragma unroll
    for (int j = 0; j < 8; ++j) s += qf[j] * ks[j];
    s += __shfl_xor(s, 1, 8);
    s += __shfl_xor(s, 2, 8);
    s += __shfl_xor(s, 4, 8);
    const float inv = 0.125f / (s * 0.125f + 1e-8f);
    bf16x8 o;
#pragma unroll
    for (int j = 0; j < 8; ++j) {
      __hip_bfloat16 bb = __float2bfloat16(qf[j] * inv);
      ((short*)&o)[j] = *(const short*)&bb;
    }
    *reinterpret_cast<bf16x8*>(&QT[(size_t)r * 512 + c]) = o;
  }
}

// ---------------------------------------------------------------------------
extern "C" void kernel_launch(void* const* d_in, const int* in_sizes, int n_in,
                              void* d_out, int out_size, void* d_ws, size_t ws_size,
                              hipStream_t stream) {
  const float* batch = (const float*)d_in[0];
  const float* w1[3] = {(const float*)d_in[1],  (const float*)d_in[7],  (const float*)d_in[13]};
  const float* b1[3] = {(const float*)d_in[2],  (const float*)d_in[8],  (const float*)d_in[14]};
  const float* w2[3] = {(const float*)d_in[3],  (const float*)d_in[9],  (const float*)d_in[15]};
  const float* b2[3] = {(const float*)d_in[4],  (const float*)d_in[10], (const float*)d_in[16]};
  const float* w3[3] = {(const float*)d_in[5],  (const float*)d_in[11], (const float*)d_in[17]};
  const float* b3[3] = {(const float*)d_in[6],  (const float*)d_in[12], (const float*)d_in[18]};
  const float* wow   = (const float*)d_in[19];
  const float* wob   = (const float*)d_in[20];

  char* ws = (char*)d_ws;
  __hip_bfloat16* XB  = (__hip_bfloat16*)(ws + OFF_XB);
  __hip_bfloat16* WT1 = (__hip_bfloat16*)(ws + OFF_WT1);
  __hip_bfloat16* WT2 = (__hip_bfloat16*)(ws + OFF_WT2);
  __hip_bfloat16* WT3 = (__hip_bfloat16*)(ws + OFF_WT3);
  __hip_bfloat16* MWT = (__hip_bfloat16*)(ws + OFF_MWT);
  __hip_bfloat16* H1  = (__hip_bfloat16*)(ws + OFF_H1);
  __hip_bfloat16* H2  = (__hip_bfloat16*)(ws + OFF_H2);
  __hip_bfloat16* QKV = (__hip_bfloat16*)(ws + OFF_QKV);
  float*          MP  = (float*)(ws + OFF_MP);
  float*          MF  = (float*)(ws + OFF_MF);
  __hip_bfloat16* QT  = (__hip_bfloat16*)(ws + OFF_QT);
  float*          OUT = (float*)d_out;

  // 1) mega-prep: all weight transposes + batch pad/convert (1 launch)
  prep<<<17920, 256, 0, stream>>>(w1[0], w1[1], w1[2], w2[0], w2[1], w2[2],
                                  w3[0], w3[1], w3[2], batch, WT1, WT2, WT3, XB);

  // 2) MLPs
  // G1 (merged q|k|v): [4096,1024]@[1024,6144] -> H1 (relu). 384 blocks,
  // 2 blocks/CU co-resident; XCD rect 8m x 6n.
  gemm_pp<<<dim3(24, 16, 1), 512, 0, stream>>>(XB, 1024, 0, WT1, 1024, 0,
                                               b1[0], b1[1], b1[2], H1, 6144, 0,
                                               32, 1, 8, 6);
  // G2 z-batched: [4096,2048]@[2048,1024] -> H2 (relu). 192 blocks; rect 4m x 2n.
  gemm_pp<<<dim3(4, 16, 3), 512, 0, stream>>>(H1, 6144, 2048, WT2, 2048, (size_t)1024 * 2048,
                                              b2[0], b2[1], b2[2], H2, 3072, 1024,
                                              64, 0, 4, 2);
  // G3 z-batched: [4096,1024]@[1024,512] -> QKV (q,k relu; v plain). 128^2.
  gemm_bt<<<dim3(4, 32, 3), 256, 0, stream>>>(H2, 3072, 1024, WT3, 1024, (size_t)512 * 1024,
                                              b3[0], b3[1], b3[2], QKV, 1536, 512,
                                              512, 1024, 3, 8, 2);

  // 3) attention reductions + fusion into out-proj operands
  kv_outer<<<dim3(32, 8), 256, 0, stream>>>(QKV, 1536, MP);
  reduce_m<<<8, 256, 0, stream>>>(MP, MF);
  mwq<<<1056, 256, 0, stream>>>(MF, wow, MWT, QKV, QT);

  // 4) fused attention+output projection: q̃ @ MW^T -> d_out fp32. 128^2.
  gemm_bt<<<dim3(8, 32, 1), 256, 0, stream>>>(QT, 512, 0, MWT, 512, 0,
                                              wob, wob, wob, OUT, 1000, 0,
                                              1000, 512, 2, 8, 4);

  (void)in_sizes; (void)n_in; (void)out_size; (void)ws_size;
}

// Round 8
// 282.272 us; speedup vs baseline: 1.5431x; 1.0476x over previous
//
#include <hip/hip_runtime.h>
#include <hip/hip_bf16.h>

// ---------------------------------------------------------------------------
// MultiHeadAttention_21887153340754
// N=4096, IN=1000(pad 1024), H1=2048, H2=1024, EMB=512, HEADS=8, depth=64, OUT=1000
//
// Attention is LINEAR in scores (no softmax):
//   out = Σ_h (q̂_h/8/den) @ (M_h @ Wo_h) + b = q̃ @ MW + b,  M_h = k̂_h^T v_h
//
// Round 8: ALL GEMMs -> gemm_fast: 128² tile, 4 waves, acc[4][4] (64 acc regs
// + ~85 arch ≈ 150 unified -> 3 waves/SIMD -> 3 blocks/CU co-resident).
// Rounds 3-7 were register-capped at 1 block/CU (acc[8][4]=128 + ~100 arch
// ≈ 228 unified -> 2 waves/SIMD), so every schedule variant idled at
// barriers (Occupancy 15%, invariant 71 µs). m114: cross-block overlap is
// what hides the per-K-tile drain. Even grid packing: G1 1536 blks (2 rounds
// @3/CU), G2 768 (3/CU exact), G3 384, out 256. XCD rect map folds z.
// ---------------------------------------------------------------------------

typedef __attribute__((ext_vector_type(4))) float f32x4;
typedef __attribute__((ext_vector_type(4))) float float4v;
typedef __attribute__((ext_vector_type(8))) short bf16x8;

// ---- workspace layout (bytes) ---------------------------------------------
static constexpr size_t OFF_XB   = 0;                      // bf16 [4096][1024]
static constexpr size_t OFF_WT1  = OFF_XB   + 8388608;     // bf16 [3][2048][1024]
static constexpr size_t OFF_WT2  = OFF_WT1  + 12582912;    // bf16 [3][1024][2048]
static constexpr size_t OFF_WT3  = OFF_WT2  + 12582912;    // bf16 [3][512][1024]
static constexpr size_t OFF_MWT  = OFF_WT3  + 3145728;     // bf16 [1024][512]  (MW^T)
static constexpr size_t OFF_B1C  = OFF_MWT  + 1048576;     // (unused hole)
static constexpr size_t OFF_H1   = OFF_B1C  + 24576;       // bf16 [4096][6144]
static constexpr size_t OFF_H2   = OFF_H1   + 50331648;    // bf16 [4096][3072]
static constexpr size_t OFF_QKV  = OFF_H2   + 25165824;    // bf16 [4096][1536]
static constexpr size_t OFF_MP   = OFF_QKV  + 12582912;    // f32  [32][8][4160]
static constexpr size_t OFF_MF   = OFF_MP   + 4259840;     // f32  [8][4160]
static constexpr size_t OFF_QT   = OFF_MF   + 133120;      // bf16 [4096][512]  (q̃)

__device__ __forceinline__ void gload16(const __hip_bfloat16* g, __hip_bfloat16* l) {
  __builtin_amdgcn_global_load_lds(
      (const __attribute__((address_space(1))) void*)g,
      (__attribute__((address_space(3))) void*)l, 16, 0, 0);
}

// XCD rect map with z folded into the linear dispatch id. HW linear id =
// (z*gy + y)*gx + x, XCD = id%8 (round-robin). Each XCD gets a cm x cn tile
// rectangle per z; slots walk m-first (keeps one B n-tile hot in its L2).
// Requires (gy/cm)*(gx/cn) == 8.
__device__ __forceinline__ void xcd_map(int gx, int gy, int cm, int cn,
                                        int& zz, int& mt, int& nt) {
  const int gid = (blockIdx.z * gy + blockIdx.y) * gx + blockIdx.x;
  const int xcd = gid & 7;
  const int slot = gid >> 3;
  const int per = cm * cn;
  zz = slot / per;
  const int rem = slot % per;
  const int nxr = gx / cn;
  const int xr = xcd % nxr, yr = xcd / nxr;
  mt = yr * cm + rem % cm;
  nt = xr * cn + rem / cm;
}

// ---- mega-prep: 9 weight transposes (fp32 [K][N] -> bf16 [N][Kpad]) + batch
__global__ __launch_bounds__(256) void prep(
    const float* __restrict__ w1a, const float* __restrict__ w1b, const float* __restrict__ w1c,
    const float* __restrict__ w2a, const float* __restrict__ w2b, const float* __restrict__ w2c,
    const float* __restrict__ w3a, const float* __restrict__ w3b, const float* __restrict__ w3c,
    const float* __restrict__ batch,
    __hip_bfloat16* __restrict__ WT1, __hip_bfloat16* __restrict__ WT2,
    __hip_bfloat16* __restrict__ WT3, __hip_bfloat16* __restrict__ XB) {
  __shared__ float tile[32][33];
  const int b = blockIdx.x, t = threadIdx.x;
  if (b >= 13824) {                                  // conv region
    int idx = (b - 13824) * 256 + t;
    int row = idx >> 8, c4 = (idx & 255) * 4;
    __hip_bfloat16 o[4];
    if (c4 < 1000) {
      float4v v = *reinterpret_cast<const float4v*>(&batch[(size_t)row * 1000 + c4]);
#pragma unroll
      for (int j = 0; j < 4; ++j) o[j] = __float2bfloat16(v[j]);
    } else {
#pragma unroll
      for (int j = 0; j < 4; ++j) o[j] = __float2bfloat16(0.f);
    }
    *reinterpret_cast<ushort4*>(&XB[(size_t)row * 1024 + c4]) =
        *reinterpret_cast<const ushort4*>(o);
    return;
  }
  const float* in; __hip_bfloat16* out; int K, N, Kpad, kb, nb;
  if (b < 6144) {
    int mat = b >> 11, r = b & 2047;
    const float* s[3] = {w1a, w1b, w1c};
    in = s[mat]; out = WT1 + (size_t)mat * 2048 * 1024;
    K = 1000; N = 2048; Kpad = 1024; kb = r & 31; nb = r >> 5;
  } else if (b < 12288) {
    int r = b - 6144; int mat = r >> 11; r &= 2047;
    const float* s[3] = {w2a, w2b, w2c};
    in = s[mat]; out = WT2 + (size_t)mat * 1024 * 2048;
    K = 2048; N = 1024; Kpad = 2048; kb = r & 63; nb = r >> 6;
  } else {
    int r = b - 12288; int mat = r >> 9; r &= 511;
    const float* s[3] = {w3a, w3b, w3c};
    in = s[mat]; out = WT3 + (size_t)mat * 512 * 1024;
    K = 1024; N = 512; Kpad = 1024; kb = r & 31; nb = r >> 5;
  }
  const int tx = t & 31, ty = t >> 5;
  const int kb32 = kb * 32, nb32 = nb * 32;
  for (int i = ty; i < 32; i += 8) {
    int k = kb32 + i, n = nb32 + tx;
    tile[i][tx] = (k < K && n < N) ? in[(size_t)k * N + n] : 0.f;
  }
  __syncthreads();
  for (int i = ty; i < 32; i += 8) {
    int n = nb32 + i, kp = kb32 + tx;
    out[(size_t)n * Kpad + kp] = __float2bfloat16(tile[tx][i]);
  }
}

// ---------------------------------------------------------------------------
// gemm_fast: 128x128 tile, BK=32, 4 waves (2m x 2n, 64x64 each), LDS 32KB
// double-buffered, one barrier + one vmcnt/lgkm drain per K-tile (round-7
// skeleton, verified 0 bank conflicts / correct). acc[4][4] keeps unified
// regs ~150 -> 3 waves/SIMD -> 3 blocks/CU co-resident (m114 overlap).
// Swizzle: 64B rows, slot = colgroup ^ ((row>>1)&3), both sides.
// epi: 1 = bf16+relu (bias by zz), 2 = f32 guarded col<nlimit (bias0),
//      3 = bf16 + relu iff zz<2, 4 = bf16+relu, bias col-select (G1 merged).
// ---------------------------------------------------------------------------
__global__ __launch_bounds__(256) void gemm_fast(
    const __hip_bfloat16* __restrict__ A, int lda, size_t Az,
    const __hip_bfloat16* __restrict__ B, int ldb, size_t Bz,
    const float* __restrict__ bias0, const float* __restrict__ bias1,
    const float* __restrict__ bias2,
    void* __restrict__ Cout, int ldc, size_t Cz,
    int nlimit, int NT, int epi, int cm, int cn) {
  __shared__ __hip_bfloat16 smA[2][4096];            // [buf][128 rows x 32]
  __shared__ __hip_bfloat16 smB[2][4096];
  const int t = threadIdx.x;
  int zz, mt, nt;
  xcd_map(gridDim.x, gridDim.y, cm, cn, zz, mt, nt);
  const int m0 = mt * 128, n0 = nt * 128;
  A += (size_t)zz * Az;
  B += (size_t)zz * Bz;

  const int w = t >> 6, l = t & 63;
  const int wm = (w >> 1) * 64, wn = (w & 1) * 64;
  const int fr = l & 15, fq = l >> 4;

  // staging: thread t covers chunks t (byte t*16) and t+256 (byte 4096+t*16).
  // linear byte L: row=L>>6, slot=(L>>4)&3, colgroup = slot ^ ((row>>1)&3)
  const int r0 = t >> 2;
  const int cg = (t & 3) ^ ((t >> 3) & 3);
  const __hip_bfloat16* gA0 = A + (size_t)(m0 + r0) * lda + cg * 8;
  const __hip_bfloat16* gA1 = gA0 + (size_t)64 * lda;
  const __hip_bfloat16* gB0 = B + (size_t)(n0 + r0) * ldb + cg * 8;
  const __hip_bfloat16* gB1 = gB0 + (size_t)64 * ldb;

  // ds_read element offsets: row*32 + (fq ^ ((row>>1)&3))*8 ; (row>>1)&3=(fr>>1)&3
  const int soff = (fq ^ ((fr >> 1) & 3)) * 8;
  int offA[4], offB[4];
#pragma unroll
  for (int i = 0; i < 4; ++i) {
    offA[i] = (wm + i * 16 + fr) * 32 + soff;
    offB[i] = (wn + i * 16 + fr) * 32 + soff;
  }

  f32x4 acc[4][4] = {};

  // prologue: stage tile 0 into buf 0
  gload16(gA0, &smA[0][w * 512]);
  gload16(gA1, &smA[0][w * 512 + 2048]);
  gload16(gB0, &smB[0][w * 512]);
  gload16(gB1, &smB[0][w * 512 + 2048]);
  asm volatile("s_waitcnt vmcnt(0)" ::: "memory");
  __builtin_amdgcn_s_barrier();

  for (int T = 0; T < NT; ++T) {
    const int cur = T & 1, nxt = cur ^ 1;
    if (T > 0) {
      asm volatile("s_waitcnt vmcnt(0) lgkmcnt(0)" ::: "memory");
      __builtin_amdgcn_sched_barrier(0);
      __builtin_amdgcn_s_barrier();
    }
    bf16x8 af[4], bf[4];
#pragma unroll
    for (int i = 0; i < 4; ++i) {
      af[i] = *reinterpret_cast<const bf16x8*>(&smA[cur][offA[i]]);
      bf[i] = *reinterpret_cast<const bf16x8*>(&smB[cur][offB[i]]);
    }
    if (T + 1 < NT) {
      const size_t ko = (size_t)(T + 1) * 32;
      gload16(gA0 + ko, &smA[nxt][w * 512]);
      gload16(gA1 + ko, &smA[nxt][w * 512 + 2048]);
      gload16(gB0 + ko, &smB[nxt][w * 512]);
      gload16(gB1 + ko, &smB[nxt][w * 512 + 2048]);
    }
    __builtin_amdgcn_s_setprio(1);
#pragma unroll
    for (int i = 0; i < 4; ++i)
#pragma unroll
      for (int j = 0; j < 4; ++j)
        acc[i][j] = __builtin_amdgcn_mfma_f32_16x16x32_bf16(af[i], bf[j], acc[i][j], 0, 0, 0);
    __builtin_amdgcn_s_setprio(0);
  }

  // epilogue
  const float* bz = (zz == 0) ? bias0 : ((zz == 1) ? bias1 : bias2);
  const bool dorelu = (epi == 1) || (epi == 4) || (epi == 3 && zz < 2);
  float bv[4];
#pragma unroll
  for (int j = 0; j < 4; ++j) {
    const int col = n0 + wn + j * 16 + fr;
    if (epi == 4) {
      const float* bsel = (col < 2048) ? bias0 : ((col < 4096) ? bias1 : bias2);
      bv[j] = bsel[col & 2047];
    } else if (epi == 2) {
      bv[j] = (col < nlimit) ? bias0[col] : 0.f;
    } else {
      bv[j] = bz[col];
    }
  }
#pragma unroll
  for (int i = 0; i < 4; ++i) {
#pragma unroll
    for (int j = 0; j < 4; ++j) {
      const int col = n0 + wn + j * 16 + fr;
#pragma unroll
      for (int rr = 0; rr < 4; ++rr) {
        const int row = m0 + wm + i * 16 + fq * 4 + rr;
        float v = acc[i][j][rr] + bv[j];
        if (dorelu) v = fmaxf(v, 0.f);
        if (epi == 2) {
          if (col < nlimit)
            ((float*)Cout)[(size_t)row * ldc + col] = v;
        } else {
          ((__hip_bfloat16*)Cout + (size_t)zz * Cz)[(size_t)row * ldc + col] =
              __float2bfloat16(v);
        }
      }
    }
  }
}

// ---- per-head partial M = kh^T vh (64x64) and ksum, over 128-row chunks ---
__global__ __launch_bounds__(256) void kv_outer(const __hip_bfloat16* __restrict__ QKV, int ld,
                                                float* __restrict__ part) {
  __shared__ __hip_bfloat16 kt[128][64];
  __shared__ __hip_bfloat16 vt[128][64];
  const int t = threadIdx.x;
  const int n0 = blockIdx.x * 128;
  const int h = blockIdx.y;
#pragma unroll
  for (int it = 0; it < 4; ++it) {
    int r = it * 32 + (t >> 3);
    int c = (t & 7) * 8;
    const __hip_bfloat16* kr = &QKV[(size_t)(n0 + r) * ld + 512 + h * 64 + c];
    const __hip_bfloat16* vr = &QKV[(size_t)(n0 + r) * ld + 1024 + h * 64 + c];
    *reinterpret_cast<bf16x8*>(&kt[r][c]) = *reinterpret_cast<const bf16x8*>(kr);
    *reinterpret_cast<bf16x8*>(&vt[r][c]) = *reinterpret_cast<const bf16x8*>(vr);
  }
  __syncthreads();
  const int i = t >> 2, j0 = (t & 3) << 4;
  float acc[16] = {};
  float ks = 0.f;
  for (int r = 0; r < 128; ++r) {
    float kv = __bfloat162float(kt[r][i]);
    ks += kv;
    bf16x8 va = *reinterpret_cast<const bf16x8*>(&vt[r][j0]);
    bf16x8 vb = *reinterpret_cast<const bf16x8*>(&vt[r][j0 + 8]);
#pragma unroll
    for (int jj = 0; jj < 8; ++jj) {
      ushort ua = (ushort)((const short*)&va)[jj];
      ushort ub = (ushort)((const short*)&vb)[jj];
      acc[jj]     += kv * __bfloat162float(*(const __hip_bfloat16*)&ua);
      acc[8 + jj] += kv * __bfloat162float(*(const __hip_bfloat16*)&ub);
    }
  }
  float* dst = part + ((size_t)blockIdx.x * 8 + h) * 4160;
#pragma unroll
  for (int jj = 0; jj < 16; ++jj) dst[i * 64 + j0 + jj] = acc[jj];
  if ((t & 3) == 0) dst[4096 + i] = ks;
}

__global__ void reduce_m(const float* __restrict__ part, float* __restrict__ Mfin) {
  int h = blockIdx.x, t = threadIdx.x;
  for (int idx = t; idx < 4160; idx += 256) {
    float s = 0.f;
    for (int c = 0; c < 32; ++c) s += part[((size_t)c * 8 + h) * 4160 + idx];
    Mfin[(size_t)h * 4160 + idx] = s;
  }
}

// ---- fused: blocks [0,32): MW^T = M_h @ Wo_h (bf16); [32,1056): q̃ --------
__global__ __launch_bounds__(256) void mwq(const float* __restrict__ Mfin,
                                           const float* __restrict__ wo,
                                           __hip_bfloat16* __restrict__ MWT,
                                           const __hip_bfloat16* __restrict__ QKV,
                                           __hip_bfloat16* __restrict__ QT) {
  const int t = threadIdx.x;
  if (blockIdx.x < 32) {
    __shared__ float Ml[64][64];
    const int h = blockIdx.x >> 2;
    const int j = (blockIdx.x & 3) * 256 + t;
    const float* M = Mfin + (size_t)h * 4160;
    for (int e = t; e < 4096; e += 256)
      Ml[e >> 6][e & 63] = M[e];
    __syncthreads();
    float wcol[64];
    const bool valid = (j < 1000);
#pragma unroll
    for (int d = 0; d < 64; ++d)
      wcol[d] = valid ? wo[(size_t)(h * 64 + d) * 1000 + j] : 0.f;
    short ob[64];
#pragma unroll
    for (int i = 0; i < 64; ++i) {
      float a = 0.f;
#pragma unroll
      for (int d = 0; d < 64; ++d) a += Ml[i][d] * wcol[d];
      __hip_bfloat16 bb = __float2bfloat16(a);
      ob[i] = *(const short*)&bb;
    }
    __hip_bfloat16* dst = MWT + (size_t)j * 512 + h * 64;
#pragma unroll
    for (int v = 0; v < 8; ++v)
      *reinterpret_cast<bf16x8*>(dst + v * 8) = *reinterpret_cast<const bf16x8*>(&ob[v * 8]);
  } else {
    const int bid = blockIdx.x - 32;
    const int r = bid * 4 + (t >> 6);
    const int c = (t & 63) * 8;
    const int h = (t & 63) >> 3;
    bf16x8 qv = *reinterpret_cast<const bf16x8*>(&QKV[(size_t)r * 1536 + c]);
    float qf[8];
#pragma unroll
    for (int j = 0; j < 8; ++j) {
      ushort u = (ushort)((const short*)&qv)[j];
      qf[j] = __bfloat162float(*(const __hip_bfloat16*)&u);
    }
    const float* ks = Mfin + (size_t)h * 4160 + 4096 + (c & 63);
    float s = 0.f;
#pragma unroll
    for (int j = 0; j < 8; ++j) s += qf[j] * ks[j];
    s += __shfl_xor(s, 1, 8);
    s += __shfl_xor(s, 2, 8);
    s += __shfl_xor(s, 4, 8);
    const float inv = 0.125f / (s * 0.125f + 1e-8f);
    bf16x8 o;
#pragma unroll
    for (int j = 0; j < 8; ++j) {
      __hip_bfloat16 bb = __float2bfloat16(qf[j] * inv);
      ((short*)&o)[j] = *(const short*)&bb;
    }
    *reinterpret_cast<bf16x8*>(&QT[(size_t)r * 512 + c]) = o;
  }
}

// ---------------------------------------------------------------------------
extern "C" void kernel_launch(void* const* d_in, const int* in_sizes, int n_in,
                              void* d_out, int out_size, void* d_ws, size_t ws_size,
                              hipStream_t stream) {
  const float* batch = (const float*)d_in[0];
  const float* w1[3] = {(const float*)d_in[1],  (const float*)d_in[7],  (const float*)d_in[13]};
  const float* b1[3] = {(const float*)d_in[2],  (const float*)d_in[8],  (const float*)d_in[14]};
  const float* w2[3] = {(const float*)d_in[3],  (const float*)d_in[9],  (const float*)d_in[15]};
  const float* b2[3] = {(const float*)d_in[4],  (const float*)d_in[10], (const float*)d_in[16]};
  const float* w3[3] = {(const float*)d_in[5],  (const float*)d_in[11], (const float*)d_in[17]};
  const float* b3[3] = {(const float*)d_in[6],  (const float*)d_in[12], (const float*)d_in[18]};
  const float* wow   = (const float*)d_in[19];
  const float* wob   = (const float*)d_in[20];

  char* ws = (char*)d_ws;
  __hip_bfloat16* XB  = (__hip_bfloat16*)(ws + OFF_XB);
  __hip_bfloat16* WT1 = (__hip_bfloat16*)(ws + OFF_WT1);
  __hip_bfloat16* WT2 = (__hip_bfloat16*)(ws + OFF_WT2);
  __hip_bfloat16* WT3 = (__hip_bfloat16*)(ws + OFF_WT3);
  __hip_bfloat16* MWT = (__hip_bfloat16*)(ws + OFF_MWT);
  __hip_bfloat16* H1  = (__hip_bfloat16*)(ws + OFF_H1);
  __hip_bfloat16* H2  = (__hip_bfloat16*)(ws + OFF_H2);
  __hip_bfloat16* QKV = (__hip_bfloat16*)(ws + OFF_QKV);
  float*          MP  = (float*)(ws + OFF_MP);
  float*          MF  = (float*)(ws + OFF_MF);
  __hip_bfloat16* QT  = (__hip_bfloat16*)(ws + OFF_QT);
  float*          OUT = (float*)d_out;

  // 1) mega-prep: all weight transposes + batch pad/convert (1 launch)
  prep<<<17920, 256, 0, stream>>>(w1[0], w1[1], w1[2], w2[0], w2[1], w2[2],
                                  w3[0], w3[1], w3[2], batch, WT1, WT2, WT3, XB);

  // 2) MLPs (all gemm_fast 128², 3 blocks/CU)
  // G1 (merged q|k|v): [4096,1024]@[1024,6144] -> H1. 1536 blocks, 2 even
  // rounds @3/CU; XCD rect 16m x 12n; epi 4 = bias col-select + relu.
  gemm_fast<<<dim3(48, 32, 1), 256, 0, stream>>>(XB, 1024, 0, WT1, 1024, 0,
                                                 b1[0], b1[1], b1[2], H1, 6144, 0,
                                                 6144, 32, 4, 16, 12);
  // G2 z-batched: [4096,2048]@[2048,1024] -> H2 (relu). 768 blocks = 3/CU
  // exact; rect 8m x 4n per z.
  gemm_fast<<<dim3(8, 32, 3), 256, 0, stream>>>(H1, 6144, 2048, WT2, 2048,
                                                (size_t)1024 * 2048,
                                                b2[0], b2[1], b2[2], H2, 3072, 1024,
                                                1024, 64, 1, 8, 4);
  // G3 z-batched: [4096,1024]@[1024,512] -> QKV (q,k relu; v plain). 384 blocks.
  gemm_fast<<<dim3(4, 32, 3), 256, 0, stream>>>(H2, 3072, 1024, WT3, 1024,
                                                (size_t)512 * 1024,
                                                b3[0], b3[1], b3[2], QKV, 1536, 512,
                                                512, 32, 3, 8, 2);

  // 3) attention reductions + fusion into out-proj operands
  kv_outer<<<dim3(32, 8), 256, 0, stream>>>(QKV, 1536, MP);
  reduce_m<<<8, 256, 0, stream>>>(MP, MF);
  mwq<<<1056, 256, 0, stream>>>(MF, wow, MWT, QKV, QT);

  // 4) fused attention+output projection: q̃ @ MW^T -> d_out fp32. 256 blocks.
  gemm_fast<<<dim3(8, 32, 1), 256, 0, stream>>>(QT, 512, 0, MWT, 512, 0,
                                                wob, wob, wob, OUT, 1000, 0,
                                                1000, 16, 2, 8, 4);

  (void)in_sizes; (void)n_in; (void)out_size; (void)ws_size;
}

// Round 9
// 278.717 us; speedup vs baseline: 1.5628x; 1.0128x over previous
//
#include <hip/hip_runtime.h>
#include <hip/hip_bf16.h>

// ---------------------------------------------------------------------------
// MultiHeadAttention_21887153340754
// N=4096, IN=1000(pad 1024), H1=2048, H2=1024, EMB=512, HEADS=8, depth=64, OUT=1000
//
// Attention is LINEAR in scores (no softmax):
//   out = Σ_h (q̂_h/8/den) @ (M_h @ Wo_h) + b = q̃ @ MW + b,  M_h = k̂_h^T v_h
//
// Round 9:
//  (1) gemm_fast -> RING-3 LDS (48 KB, still 3 blocks/CU) with COUNTED
//      vmcnt(4): each staging load now has ~2 K-tile-times of flight
//      (~2x L3/HBM latency) instead of ~1 (round-8 vmcnt(0)-per-tile was
//      latency-bound: 2660 cy/K-tile vs 233 cy MFMA content).
//      Ledger: prologue stages tiles 0,1; at tile T wait vmcnt(4) [own tile-T
//      stages done, tile-T+1's 4 in flight] -> barrier [all waves' T-stages
//      done] -> ds_read buf T%3 -> stage T+2 into buf (T+2)%3 (= buf read at
//      T-1; safe: every wave drained its T-1 reads before its T-1 MFMAs,
//      which precede barrier T) -> MFMA. Last tile: vmcnt(0).
//  (2) prep rewritten: 64x64 f32 tiles, coalesced float4 reads, LDS [64][65]
//      transpose (2-way bank alias = free), bf16x8 writes. 17920 -> 7552 blks.
// ---------------------------------------------------------------------------

typedef __attribute__((ext_vector_type(4))) float f32x4;
typedef __attribute__((ext_vector_type(4))) float float4v;
typedef __attribute__((ext_vector_type(8))) short bf16x8;

// ---- workspace layout (bytes) ---------------------------------------------
static constexpr size_t OFF_XB   = 0;                      // bf16 [4096][1024]
static constexpr size_t OFF_WT1  = OFF_XB   + 8388608;     // bf16 [3][2048][1024]
static constexpr size_t OFF_WT2  = OFF_WT1  + 12582912;    // bf16 [3][1024][2048]
static constexpr size_t OFF_WT3  = OFF_WT2  + 12582912;    // bf16 [3][512][1024]
static constexpr size_t OFF_MWT  = OFF_WT3  + 3145728;     // bf16 [1024][512]  (MW^T)
static constexpr size_t OFF_B1C  = OFF_MWT  + 1048576;     // (unused hole)
static constexpr size_t OFF_H1   = OFF_B1C  + 24576;       // bf16 [4096][6144]
static constexpr size_t OFF_H2   = OFF_H1   + 50331648;    // bf16 [4096][3072]
static constexpr size_t OFF_QKV  = OFF_H2   + 25165824;    // bf16 [4096][1536]
static constexpr size_t OFF_MP   = OFF_QKV  + 12582912;    // f32  [32][8][4160]
static constexpr size_t OFF_MF   = OFF_MP   + 4259840;     // f32  [8][4160]
static constexpr size_t OFF_QT   = OFF_MF   + 133120;      // bf16 [4096][512]  (q̃)

__device__ __forceinline__ void gload16(const __hip_bfloat16* g, __hip_bfloat16* l) {
  __builtin_amdgcn_global_load_lds(
      (const __attribute__((address_space(1))) void*)g,
      (__attribute__((address_space(3))) void*)l, 16, 0, 0);
}

// XCD rect map with z folded into the linear dispatch id. HW linear id =
// (z*gy + y)*gx + x, XCD = id%8 (round-robin). Each XCD gets a cm x cn tile
// rectangle per z; slots walk m-first. Requires (gy/cm)*(gx/cn) == 8.
__device__ __forceinline__ void xcd_map(int gx, int gy, int cm, int cn,
                                        int& zz, int& mt, int& nt) {
  const int gid = (blockIdx.z * gy + blockIdx.y) * gx + blockIdx.x;
  const int xcd = gid & 7;
  const int slot = gid >> 3;
  const int per = cm * cn;
  zz = slot / per;
  const int rem = slot % per;
  const int nxr = gx / cn;
  const int xr = xcd % nxr, yr = xcd / nxr;
  mt = yr * cm + rem % cm;
  nt = xr * cn + rem / cm;
}

// ---- mega-prep v2: 9 weight transposes (fp32 [K][N] -> bf16 [N][Kpad]) ----
// 64x64 tiles, 256 threads; coalesced float4 reads, [64][65] LDS transpose,
// bf16x8 writes. Blocks: [0,1536) w1 | [1536,3072) w2 | [3072,3456) w3 |
// [3456,7552) batch fp32 [4096][1000] -> bf16 [4096][1024].
__global__ __launch_bounds__(256) void prep(
    const float* __restrict__ w1a, const float* __restrict__ w1b, const float* __restrict__ w1c,
    const float* __restrict__ w2a, const float* __restrict__ w2b, const float* __restrict__ w2c,
    const float* __restrict__ w3a, const float* __restrict__ w3b, const float* __restrict__ w3c,
    const float* __restrict__ batch,
    __hip_bfloat16* __restrict__ WT1, __hip_bfloat16* __restrict__ WT2,
    __hip_bfloat16* __restrict__ WT3, __hip_bfloat16* __restrict__ XB) {
  const int b = blockIdx.x, t = threadIdx.x;
  if (b >= 3456) {                                   // batch conv region
    int idx = (b - 3456) * 256 + t;
    int row = idx >> 8, c4 = (idx & 255) * 4;
    __hip_bfloat16 o[4];
    if (c4 < 1000) {
      float4v v = *reinterpret_cast<const float4v*>(&batch[(size_t)row * 1000 + c4]);
#pragma unroll
      for (int j = 0; j < 4; ++j) o[j] = __float2bfloat16(v[j]);
    } else {
#pragma unroll
      for (int j = 0; j < 4; ++j) o[j] = __float2bfloat16(0.f);
    }
    *reinterpret_cast<ushort4*>(&XB[(size_t)row * 1024 + c4]) =
        *reinterpret_cast<const ushort4*>(o);
    return;
  }
  __shared__ float tl[64][65];
  const float* in; __hip_bfloat16* out; int K, N, Kpad, kb, nb;
  if (b < 1536) {                                    // w1: 16 ktiles x 32 ntiles
    int mat = b / 512, r = b % 512;
    const float* s[3] = {w1a, w1b, w1c};
    in = s[mat]; out = WT1 + (size_t)mat * 2048 * 1024;
    K = 1000; N = 2048; Kpad = 1024; kb = r & 15; nb = r >> 4;
  } else if (b < 3072) {                             // w2: 32 ktiles x 16 ntiles
    int r = b - 1536; int mat = r / 512; r %= 512;
    const float* s[3] = {w2a, w2b, w2c};
    in = s[mat]; out = WT2 + (size_t)mat * 1024 * 2048;
    K = 2048; N = 1024; Kpad = 2048; kb = r & 31; nb = r >> 5;
  } else {                                           // w3: 16 ktiles x 8 ntiles
    int r = b - 3072; int mat = r / 128; r %= 128;
    const float* s[3] = {w3a, w3b, w3c};
    in = s[mat]; out = WT3 + (size_t)mat * 512 * 1024;
    K = 1024; N = 512; Kpad = 1024; kb = r & 15; nb = r >> 4;
  }
  const int kb64 = kb * 64, nb64 = nb * 64;
  const int trow = t >> 4, tc4 = (t & 15) * 4;
#pragma unroll
  for (int it = 0; it < 4; ++it) {
    const int kl = it * 16 + trow;
    const int k = kb64 + kl;
    float4v v = {0.f, 0.f, 0.f, 0.f};
    if (k < K) v = *reinterpret_cast<const float4v*>(&in[(size_t)k * N + nb64 + tc4]);
    tl[kl][tc4 + 0] = v[0]; tl[kl][tc4 + 1] = v[1];
    tl[kl][tc4 + 2] = v[2]; tl[kl][tc4 + 3] = v[3];
  }
  __syncthreads();
  const int ln = t >> 2, ks = (t & 3) * 16;
  short ob[16];
#pragma unroll
  for (int u = 0; u < 16; ++u) {
    __hip_bfloat16 bb = __float2bfloat16(tl[ks + u][ln]);
    ob[u] = *(const short*)&bb;
  }
  __hip_bfloat16* dst = out + (size_t)(nb64 + ln) * Kpad + kb64 + ks;
  *reinterpret_cast<bf16x8*>(dst) = *reinterpret_cast<const bf16x8*>(&ob[0]);
  *reinterpret_cast<bf16x8*>(dst + 8) = *reinterpret_cast<const bf16x8*>(&ob[8]);
}

// ---------------------------------------------------------------------------
// gemm_fast: 128x128 tile, BK=32, 4 waves (2m x 2n, 64x64 each), RING-3 LDS
// (48 KB), counted vmcnt(4), 3 blocks/CU. One barrier per K-tile.
// Swizzle: 64B rows, slot = colgroup ^ ((row>>1)&3), both sides.
// epi: 1 = bf16+relu (bias by zz), 2 = f32 guarded col<nlimit (bias0),
//      3 = bf16 + relu iff zz<2, 4 = bf16+relu, bias col-select (G1 merged).
// ---------------------------------------------------------------------------
__global__ __launch_bounds__(256) void gemm_fast(
    const __hip_bfloat16* __restrict__ A, int lda, size_t Az,
    const __hip_bfloat16* __restrict__ B, int ldb, size_t Bz,
    const float* __restrict__ bias0, const float* __restrict__ bias1,
    const float* __restrict__ bias2,
    void* __restrict__ Cout, int ldc, size_t Cz,
    int nlimit, int NT, int epi, int cm, int cn) {
  __shared__ __hip_bfloat16 smA[3][4096];            // [buf][128 rows x 32]
  __shared__ __hip_bfloat16 smB[3][4096];
  const int t = threadIdx.x;
  int zz, mt, nt;
  xcd_map(gridDim.x, gridDim.y, cm, cn, zz, mt, nt);
  const int m0 = mt * 128, n0 = nt * 128;
  A += (size_t)zz * Az;
  B += (size_t)zz * Bz;

  const int w = t >> 6, l = t & 63;
  const int wm = (w >> 1) * 64, wn = (w & 1) * 64;
  const int fr = l & 15, fq = l >> 4;

  // staging: linear byte L: row=L>>6, slot=(L>>4)&3, colgroup = slot^((row>>1)&3)
  const int r0 = t >> 2;
  const int cg = (t & 3) ^ ((t >> 3) & 3);
  const __hip_bfloat16* gA0 = A + (size_t)(m0 + r0) * lda + cg * 8;
  const __hip_bfloat16* gA1 = gA0 + (size_t)64 * lda;
  const __hip_bfloat16* gB0 = B + (size_t)(n0 + r0) * ldb + cg * 8;
  const __hip_bfloat16* gB1 = gB0 + (size_t)64 * ldb;

  // ds_read element offsets: row*32 + (fq ^ ((row>>1)&3))*8
  const int soff = (fq ^ ((fr >> 1) & 3)) * 8;
  int offA[4], offB[4];
#pragma unroll
  for (int i = 0; i < 4; ++i) {
    offA[i] = (wm + i * 16 + fr) * 32 + soff;
    offB[i] = (wn + i * 16 + fr) * 32 + soff;
  }

  f32x4 acc[4][4] = {};

#define STG(BUF, KT) do {                                                      \
    const size_t ko_ = (size_t)(KT) * 32;                                      \
    gload16(gA0 + ko_, &smA[BUF][w * 512]);                                    \
    gload16(gA1 + ko_, &smA[BUF][w * 512 + 2048]);                             \
    gload16(gB0 + ko_, &smB[BUF][w * 512]);                                    \
    gload16(gB1 + ko_, &smB[BUF][w * 512 + 2048]);                             \
  } while (0)

  // prologue: stage tiles 0,1 into bufs 0,1 (8 loads/wave outstanding)
  STG(0, 0);
  STG(1, 1);

  int cur = 0;
  for (int T = 0; T < NT; ++T) {
    if (T == NT - 1)
      asm volatile("s_waitcnt vmcnt(0)" ::: "memory");
    else
      asm volatile("s_waitcnt vmcnt(4)" ::: "memory");   // tile T's stages done
    __builtin_amdgcn_s_barrier();                        // all waves' T-stages done
    __builtin_amdgcn_sched_barrier(0);
    bf16x8 af[4], bf[4];
#pragma unroll
    for (int i = 0; i < 4; ++i) {
      af[i] = *reinterpret_cast<const bf16x8*>(&smA[cur][offA[i]]);
      bf[i] = *reinterpret_cast<const bf16x8*>(&smB[cur][offB[i]]);
    }
    if (T + 2 < NT) {
      const int nb_ = (cur + 2 >= 3) ? cur - 1 : cur + 2;
      STG(nb_, T + 2);
    }
    __builtin_amdgcn_s_setprio(1);
#pragma unroll
    for (int i = 0; i < 4; ++i)
#pragma unroll
      for (int j = 0; j < 4; ++j)
        acc[i][j] = __builtin_amdgcn_mfma_f32_16x16x32_bf16(af[i], bf[j], acc[i][j], 0, 0, 0);
    __builtin_amdgcn_s_setprio(0);
    cur = (cur + 1 >= 3) ? 0 : cur + 1;
  }
#undef STG

  // epilogue
  const float* bz = (zz == 0) ? bias0 : ((zz == 1) ? bias1 : bias2);
  const bool dorelu = (epi == 1) || (epi == 4) || (epi == 3 && zz < 2);
  float bv[4];
#pragma unroll
  for (int j = 0; j < 4; ++j) {
    const int col = n0 + wn + j * 16 + fr;
    if (epi == 4) {
      const float* bsel = (col < 2048) ? bias0 : ((col < 4096) ? bias1 : bias2);
      bv[j] = bsel[col & 2047];
    } else if (epi == 2) {
      bv[j] = (col < nlimit) ? bias0[col] : 0.f;
    } else {
      bv[j] = bz[col];
    }
  }
#pragma unroll
  for (int i = 0; i < 4; ++i) {
#pragma unroll
    for (int j = 0; j < 4; ++j) {
      const int col = n0 + wn + j * 16 + fr;
#pragma unroll
      for (int rr = 0; rr < 4; ++rr) {
        const int row = m0 + wm + i * 16 + fq * 4 + rr;
        float v = acc[i][j][rr] + bv[j];
        if (dorelu) v = fmaxf(v, 0.f);
        if (epi == 2) {
          if (col < nlimit)
            ((float*)Cout)[(size_t)row * ldc + col] = v;
        } else {
          ((__hip_bfloat16*)Cout + (size_t)zz * Cz)[(size_t)row * ldc + col] =
              __float2bfloat16(v);
        }
      }
    }
  }
}

// ---- per-head partial M = kh^T vh (64x64) and ksum, over 128-row chunks ---
__global__ __launch_bounds__(256) void kv_outer(const __hip_bfloat16* __restrict__ QKV, int ld,
                                                float* __restrict__ part) {
  __shared__ __hip_bfloat16 kt[128][64];
  __shared__ __hip_bfloat16 vt[128][64];
  const int t = threadIdx.x;
  const int n0 = blockIdx.x * 128;
  const int h = blockIdx.y;
#pragma unroll
  for (int it = 0; it < 4; ++it) {
    int r = it * 32 + (t >> 3);
    int c = (t & 7) * 8;
    const __hip_bfloat16* kr = &QKV[(size_t)(n0 + r) * ld + 512 + h * 64 + c];
    const __hip_bfloat16* vr = &QKV[(size_t)(n0 + r) * ld + 1024 + h * 64 + c];
    *reinterpret_cast<bf16x8*>(&kt[r][c]) = *reinterpret_cast<const bf16x8*>(kr);
    *reinterpret_cast<bf16x8*>(&vt[r][c]) = *reinterpret_cast<const bf16x8*>(vr);
  }
  __syncthreads();
  const int i = t >> 2, j0 = (t & 3) << 4;
  float acc[16] = {};
  float ks = 0.f;
  for (int r = 0; r < 128; ++r) {
    float kv = __bfloat162float(kt[r][i]);
    ks += kv;
    bf16x8 va = *reinterpret_cast<const bf16x8*>(&vt[r][j0]);
    bf16x8 vb = *reinterpret_cast<const bf16x8*>(&vt[r][j0 + 8]);
#pragma unroll
    for (int jj = 0; jj < 8; ++jj) {
      ushort ua = (ushort)((const short*)&va)[jj];
      ushort ub = (ushort)((const short*)&vb)[jj];
      acc[jj]     += kv * __bfloat162float(*(const __hip_bfloat16*)&ua);
      acc[8 + jj] += kv * __bfloat162float(*(const __hip_bfloat16*)&ub);
    }
  }
  float* dst = part + ((size_t)blockIdx.x * 8 + h) * 4160;
#pragma unroll
  for (int jj = 0; jj < 16; ++jj) dst[i * 64 + j0 + jj] = acc[jj];
  if ((t & 3) == 0) dst[4096 + i] = ks;
}

__global__ void reduce_m(const float* __restrict__ part, float* __restrict__ Mfin) {
  int h = blockIdx.x, t = threadIdx.x;
  for (int idx = t; idx < 4160; idx += 256) {
    float s = 0.f;
    for (int c = 0; c < 32; ++c) s += part[((size_t)c * 8 + h) * 4160 + idx];
    Mfin[(size_t)h * 4160 + idx] = s;
  }
}

// ---- fused: blocks [0,32): MW^T = M_h @ Wo_h (bf16); [32,1056): q̃ --------
__global__ __launch_bounds__(256) void mwq(const float* __restrict__ Mfin,
                                           const float* __restrict__ wo,
                                           __hip_bfloat16* __restrict__ MWT,
                                           const __hip_bfloat16* __restrict__ QKV,
                                           __hip_bfloat16* __restrict__ QT) {
  const int t = threadIdx.x;
  if (blockIdx.x < 32) {
    __shared__ float Ml[64][64];
    const int h = blockIdx.x >> 2;
    const int j = (blockIdx.x & 3) * 256 + t;
    const float* M = Mfin + (size_t)h * 4160;
    for (int e = t; e < 4096; e += 256)
      Ml[e >> 6][e & 63] = M[e];
    __syncthreads();
    float wcol[64];
    const bool valid = (j < 1000);
#pragma unroll
    for (int d = 0; d < 64; ++d)
      wcol[d] = valid ? wo[(size_t)(h * 64 + d) * 1000 + j] : 0.f;
    short ob[64];
#pragma unroll
    for (int i = 0; i < 64; ++i) {
      float a = 0.f;
#pragma unroll
      for (int d = 0; d < 64; ++d) a += Ml[i][d] * wcol[d];
      __hip_bfloat16 bb = __float2bfloat16(a);
      ob[i] = *(const short*)&bb;
    }
    __hip_bfloat16* dst = MWT + (size_t)j * 512 + h * 64;
#pragma unroll
    for (int v = 0; v < 8; ++v)
      *reinterpret_cast<bf16x8*>(dst + v * 8) = *reinterpret_cast<const bf16x8*>(&ob[v * 8]);
  } else {
    const int bid = blockIdx.x - 32;
    const int r = bid * 4 + (t >> 6);
    const int c = (t & 63) * 8;
    const int h = (t & 63) >> 3;
    bf16x8 qv = *reinterpret_cast<const bf16x8*>(&QKV[(size_t)r * 1536 + c]);
    float qf[8];
#pragma unroll
    for (int j = 0; j < 8; ++j) {
      ushort u = (ushort)((const short*)&qv)[j];
      qf[j] = __bfloat162float(*(const __hip_bfloat16*)&u);
    }
    const float* ks = Mfin + (size_t)h * 4160 + 4096 + (c & 63);
    float s = 0.f;
#pragma unroll
    for (int j = 0; j < 8; ++j) s += qf[j] * ks[j];
    s += __shfl_xor(s, 1, 8);
    s += __shfl_xor(s, 2, 8);
    s += __shfl_xor(s, 4, 8);
    const float inv = 0.125f / (s * 0.125f + 1e-8f);
    bf16x8 o;
#pragma unroll
    for (int j = 0; j < 8; ++j) {
      __hip_bfloat16 bb = __float2bfloat16(qf[j] * inv);
      ((short*)&o)[j] = *(const short*)&bb;
    }
    *reinterpret_cast<bf16x8*>(&QT[(size_t)r * 512 + c]) = o;
  }
}

// ---------------------------------------------------------------------------
extern "C" void kernel_launch(void* const* d_in, const int* in_sizes, int n_in,
                              void* d_out, int out_size, void* d_ws, size_t ws_size,
                              hipStream_t stream) {
  const float* batch = (const float*)d_in[0];
  const float* w1[3] = {(const float*)d_in[1],  (const float*)d_in[7],  (const float*)d_in[13]};
  const float* b1[3] = {(const float*)d_in[2],  (const float*)d_in[8],  (const float*)d_in[14]};
  const float* w2[3] = {(const float*)d_in[3],  (const float*)d_in[9],  (const float*)d_in[15]};
  const float* b2[3] = {(const float*)d_in[4],  (const float*)d_in[10], (const float*)d_in[16]};
  const float* w3[3] = {(const float*)d_in[5],  (const float*)d_in[11], (const float*)d_in[17]};
  const float* b3[3] = {(const float*)d_in[6],  (const float*)d_in[12], (const float*)d_in[18]};
  const float* wow   = (const float*)d_in[19];
  const float* wob   = (const float*)d_in[20];

  char* ws = (char*)d_ws;
  __hip_bfloat16* XB  = (__hip_bfloat16*)(ws + OFF_XB);
  __hip_bfloat16* WT1 = (__hip_bfloat16*)(ws + OFF_WT1);
  __hip_bfloat16* WT2 = (__hip_bfloat16*)(ws + OFF_WT2);
  __hip_bfloat16* WT3 = (__hip_bfloat16*)(ws + OFF_WT3);
  __hip_bfloat16* MWT = (__hip_bfloat16*)(ws + OFF_MWT);
  __hip_bfloat16* H1  = (__hip_bfloat16*)(ws + OFF_H1);
  __hip_bfloat16* H2  = (__hip_bfloat16*)(ws + OFF_H2);
  __hip_bfloat16* QKV = (__hip_bfloat16*)(ws + OFF_QKV);
  float*          MP  = (float*)(ws + OFF_MP);
  float*          MF  = (float*)(ws + OFF_MF);
  __hip_bfloat16* QT  = (__hip_bfloat16*)(ws + OFF_QT);
  float*          OUT = (float*)d_out;

  // 1) mega-prep: all weight transposes + batch pad/convert (1 launch)
  prep<<<7552, 256, 0, stream>>>(w1[0], w1[1], w1[2], w2[0], w2[1], w2[2],
                                 w3[0], w3[1], w3[2], batch, WT1, WT2, WT3, XB);

  // 2) MLPs (all gemm_fast 128², ring-3, 3 blocks/CU)
  // G1 (merged q|k|v): [4096,1024]@[1024,6144] -> H1. 1536 blocks; rect 16x12.
  gemm_fast<<<dim3(48, 32, 1), 256, 0, stream>>>(XB, 1024, 0, WT1, 1024, 0,
                                                 b1[0], b1[1], b1[2], H1, 6144, 0,
                                                 6144, 32, 4, 16, 12);
  // G2 z-batched: [4096,2048]@[2048,1024] -> H2 (relu). 768 blocks; rect 8x4.
  gemm_fast<<<dim3(8, 32, 3), 256, 0, stream>>>(H1, 6144, 2048, WT2, 2048,
                                                (size_t)1024 * 2048,
                                                b2[0], b2[1], b2[2], H2, 3072, 1024,
                                                1024, 64, 1, 8, 4);
  // G3 z-batched: [4096,1024]@[1024,512] -> QKV (q,k relu; v plain). 384 blocks.
  gemm_fast<<<dim3(4, 32, 3), 256, 0, stream>>>(H2, 3072, 1024, WT3, 1024,
                                                (size_t)512 * 1024,
                                                b3[0], b3[1], b3[2], QKV, 1536, 512,
                                                512, 32, 3, 8, 2);

  // 3) attention reductions + fusion into out-proj operands
  kv_outer<<<dim3(32, 8), 256, 0, stream>>>(QKV, 1536, MP);
  reduce_m<<<8, 256, 0, stream>>>(MP, MF);
  mwq<<<1056, 256, 0, stream>>>(MF, wow, MWT, QKV, QT);

  // 4) fused attention+output projection: q̃ @ MW^T -> d_out fp32. 256 blocks.
  gemm_fast<<<dim3(8, 32, 1), 256, 0, stream>>>(QT, 512, 0, MWT, 512, 0,
                                                wob, wob, wob, OUT, 1000, 0,
                                                1000, 16, 2, 8, 4);

  (void)in_sizes; (void)n_in; (void)out_size; (void)ws_size;
}